// Round 3
// baseline (595.440 us; speedup 1.0000x reference)
//
#include <hip/hip_runtime.h>
#include <hip/hip_bf16.h>

// Show-Attend-Tell attention. B=128, P=196, E=2048, H=1024, A=1024.
// fp32 in / fp32 out (established round 6; passed absmax 1.95e-3).
// Round 10:
//   - k_cvt pre-converts enc -> bf16 g_enc (103 MB module global) once.
//   - GEMM: BOTH A and B staged via global_load_lds with pre-swizzled global
//     sources (rule 21 / m173). Hot loop has NO cvt, NO ds_write, NO areg:
//     drain -> barrier -> 8x gl16 (next tile) -> ds_read_b128 frags -> MFMA.
//     LDS 65 KB (A pad-72 buffer replaced by XOR-chunk-swizzled [128][64]).
//   - XCD-aware bijective block swizzle kept (round 9: FETCH 815->175 MB).
// Intermediates inside d_out (fp32, 287232 elems total):
//   bytes [0      : 524288)  att2' fp32 [B][A]   (dead after GEMM)
//   bytes [524288 : 624640)  scores fp32 [M]     (dead after softmax)
//   elems [262144 : 287232)  alpha fp32 (final)
//   elems [0      : 262144)  context fp32 (final, written LAST by k_context)

#define B_   128
#define P_   196
#define E_   2048
#define H_   1024
#define A_   1024
#define M_   (B_ * P_)      // 25088
#define NKSTEP (E_ / 64)    // 32

typedef __bf16 bf16x8 __attribute__((ext_vector_type(8)));
typedef float f32x4 __attribute__((ext_vector_type(4)));

// One-time converted operands (module globals):
__device__ __bf16 g_wt[(size_t)A_ * E_];    // 4 MB:  Wt[a][e] = bf16 W_enc[e][a]
__device__ __bf16 g_enc[(size_t)M_ * E_];   // 103 MB: bf16 enc[m][e]

__device__ __forceinline__ bf16x8 cvt8r(const float4 a, const float4 b) {
    bf16x8 r;
    r[0] = (__bf16)a.x; r[1] = (__bf16)a.y; r[2] = (__bf16)a.z; r[3] = (__bf16)a.w;
    r[4] = (__bf16)b.x; r[5] = (__bf16)b.y; r[6] = (__bf16)b.z; r[7] = (__bf16)b.w;
    return r;
}

// async 16B global->LDS (lds dest wave-uniform; HW adds lane*16)
__device__ __forceinline__ void gl16(const void* g, void* l) {
    __builtin_amdgcn_global_load_lds(
        (const __attribute__((address_space(1))) unsigned int*)g,
        (__attribute__((address_space(3))) unsigned int*)l, 16, 0, 0);
}

// ---------------------------------------------------------------------------
// K-1: g_enc = bf16(enc).  Grid-stride, 16B loads / 16B stores. ~50 us.
// ---------------------------------------------------------------------------
__global__ __launch_bounds__(256) void k_cvt(const float* __restrict__ enc) {
    const size_t n = (size_t)M_ * E_;       // 51,380,224 (divisible by 8)
    const size_t stride = (size_t)gridDim.x * 256 * 8;
    for (size_t i = ((size_t)blockIdx.x * 256 + threadIdx.x) * 8; i < n;
         i += stride) {
        const float4 a = *(const float4*)(enc + i);
        const float4 b = *(const float4*)(enc + i + 4);
        *(bf16x8*)&g_enc[i] = cvt8r(a, b);
    }
}

// ---------------------------------------------------------------------------
// K0: Wt[a][e] = bf16(W_enc[e][a]).  64x64 tiles, one-shot (~5 us).
// ---------------------------------------------------------------------------
__global__ __launch_bounds__(256) void k_wt(const float* __restrict__ w) {
    __shared__ __bf16 tile[64][72];     // [a][e], stride 72 keeps 16B align
    const int t = threadIdx.x;
    const int a0 = blockIdx.x * 64, e0 = blockIdx.y * 64;
    const int er = t >> 2, c0 = (t & 3) * 16;
#pragma unroll
    for (int j = 0; j < 4; ++j) {
        const float4 v =
            *(const float4*)&w[(size_t)(e0 + er) * A_ + a0 + c0 + j * 4];
        tile[c0 + j * 4 + 0][er] = (__bf16)v.x;
        tile[c0 + j * 4 + 1][er] = (__bf16)v.y;
        tile[c0 + j * 4 + 2][er] = (__bf16)v.z;
        tile[c0 + j * 4 + 3][er] = (__bf16)v.w;
    }
    __syncthreads();
    const int ar = t >> 2, es0 = (t & 3) * 16;
    *(bf16x8*)&g_wt[(size_t)(a0 + ar) * E_ + e0 + es0] =
        *(const bf16x8*)&tile[ar][es0];
    *(bf16x8*)&g_wt[(size_t)(a0 + ar) * E_ + e0 + es0 + 8] =
        *(const bf16x8*)&tile[ar][es0 + 8];
}

// ---------------------------------------------------------------------------
// K1: zero scores; att2p[b][a] = b_enc[a]+b_dec[a]+sum_h dh[b][h]*W_dec[h][a]
// grid (8 a-chunks, 16 b-groups of 8). Each W_dec load feeds 8 batch rows.
// ---------------------------------------------------------------------------
__global__ __launch_bounds__(256) void k_att2(
    const float* __restrict__ dh, const float* __restrict__ wdec,
    const float* __restrict__ benc, const float* __restrict__ bdec,
    float* __restrict__ scores, float* __restrict__ att2p) {
    const int t = threadIdx.x;
    const int a0 = blockIdx.x * 128;
    const int b0 = blockIdx.y * 8;
    const int bid = blockIdx.y * 8 + blockIdx.x;     // 0..127
    const int gi = bid * 256 + t;
    if (gi < M_) scores[gi] = 0.f;          // zero before GEMM's atomicAdd
    __shared__ float hs[8][H_];             // 32 KB
    __shared__ float red[256][8];           // 8 KB
    for (int i = t; i < 8 * H_; i += 256)
        hs[i >> 10][i & 1023] = dh[(size_t)(b0 + (i >> 10)) * H_ + (i & 1023)];
    __syncthreads();
    const int a = a0 + (t & 127);
    const int h0 = (t >> 7) * 512;
    float acc[8] = {};
#pragma unroll 4
    for (int h = 0; h < 512; ++h) {
        const float w = wdec[(size_t)(h0 + h) * A_ + a];
#pragma unroll
        for (int j = 0; j < 8; ++j) acc[j] += hs[j][h0 + h] * w;
    }
#pragma unroll
    for (int j = 0; j < 8; ++j) red[t][j] = acc[j];
    __syncthreads();
    if (t < 128) {
        const float bb = benc[a0 + t] + bdec[a0 + t];
#pragma unroll
        for (int j = 0; j < 8; ++j)
            att2p[(size_t)(b0 + j) * A_ + a0 + t] =
                red[t][j] + red[t + 128][j] + bb;
    }
}

// ---------------------------------------------------------------------------
// K2: fused GEMM(att1, bf16 MFMA) + bias + relu + W_full row-reduce ->
// atomicAdd into scores[M]. C-tile 128m x 128n, BK=64, dbuf LDS.
// 4 waves: wm=wave>>1, wn=wave&1; each wave 64x64 via 4x4 frags 16x16x32.
// Both A and B tiles: global_load_lds direct, LDS linear [128 rows][64 k]
// bf16 (128 B/row); global SOURCE carries the inverse XOR-chunk swizzle:
//   LDS[row][chunk] (16B chunks) holds source chunk (chunk ^ (row&7)).
// Staging: op i of wave w covers rows i*32 + w*8 + (lane>>3), chunk lane&7;
// source = base + row*4096 + ((lane&7)^(lane>>3))*16 + kstep*128.
// Frag read: byte = row*128 + ((ks*64+q*16) ^ ((r&7)<<4)) -> conflict-free
// per cycle-group (8 consecutive lanes hit 8 distinct 16B chunk slots).
// One raw s_barrier per K-step preceded by vmcnt(0)+lgkmcnt(0).
// XCD swizzle: L = (orig&7)*196 + orig/8 (bijective, nwg=1568=8*196).
// ---------------------------------------------------------------------------
__global__ __launch_bounds__(256, 2) void k_gemm_scores(
    const float* __restrict__ att2p,    // [B_][A_] fp32
    const float* __restrict__ wfull,    // [A_] fp32
    float* __restrict__ scores) {       // [M_] fp32
    __shared__ __align__(16) __bf16 As[2][128 * 64];
    __shared__ __align__(16) __bf16 Bs[2][128 * 64];
    __shared__ float red[2][128];

    const int t = threadIdx.x;
    const int lane = t & 63;
    const int wave = t >> 6;
    const int wm = wave >> 1, wn = wave & 1;
    const int q = lane >> 4, r = lane & 15;
    const int orig = blockIdx.y * 8 + blockIdx.x;      // 0..1567
    const int L = (orig & 7) * (M_ / 128) + (orig >> 3);
    const int bn = L & 7, bm = L >> 3;
    const int m0 = bm * 128, n0 = bn * 128;

    // staging addresses (bytes). row stride of both g_enc and g_wt = 4096 B.
    const int rbase = wave * 8 + (lane >> 3);            // 0..31
    const int cx = ((t & 7) ^ ((t >> 3) & 7)) * 16;      // swizzled chunk
    const char* pa = (const char*)g_enc + (size_t)(m0 + rbase) * 4096 + cx;
    const char* pb = (const char*)g_wt  + (size_t)(n0 + rbase) * 4096 + cx;
    char* ad0 = (char*)&As[0][0] + wave * 1024;
    char* ad1 = (char*)&As[1][0] + wave * 1024;
    char* bd0 = (char*)&Bs[0][0] + wave * 1024;
    char* bd1 = (char*)&Bs[1][0] + wave * 1024;

    f32x4 acc[4][4] = {};

    // ---- prologue: stage tile 0 into buffer 0 ----
#pragma unroll
    for (int i = 0; i < 4; ++i)
        gl16(pa + (size_t)i * 131072, ad0 + i * 4096);
#pragma unroll
    for (int i = 0; i < 4; ++i)
        gl16(pb + (size_t)i * 131072, bd0 + i * 4096);

    int cur = 0;
    for (int kt = 0; kt < NKSTEP; ++kt) {
        // buf[cur] ready once our own outstanding ops drain + all waves sync
        asm volatile("s_waitcnt vmcnt(0)" ::: "memory");
        asm volatile("s_waitcnt lgkmcnt(0)" ::: "memory");
        __builtin_amdgcn_s_barrier();

        const char* AsC = (const char*)&As[cur][0];
        const char* BsC = (const char*)&Bs[cur][0];

        if (kt + 1 < NKSTEP) {  // stage tile kt+1 into the other buffer
            char* ad = cur ? ad0 : ad1;
            char* bd = cur ? bd0 : bd1;
            const size_t ko = (size_t)(kt + 1) * 128;
#pragma unroll
            for (int i = 0; i < 4; ++i)
                gl16(pa + (size_t)i * 131072 + ko, ad + i * 4096);
#pragma unroll
            for (int i = 0; i < 4; ++i)
                gl16(pb + (size_t)i * 131072 + ko, bd + i * 4096);
        }

        // compute tile kt (plain C++: compiler handles lgkm waits)
#pragma unroll
        for (int ks = 0; ks < 2; ++ks) {
            bf16x8 af[4], bfv[4];
#pragma unroll
            for (int f = 0; f < 4; ++f) {
                const int mf = wm * 64 + f * 16 + r;      // mf&7 == r&7
                af[f] = *(const bf16x8*)(AsC + mf * 128 +
                        ((ks * 64 + q * 16) ^ ((r & 7) << 4)));
            }
#pragma unroll
            for (int f = 0; f < 4; ++f) {
                const int nf = wn * 64 + f * 16 + r;      // nf&7 == r&7
                bfv[f] = *(const bf16x8*)(BsC + nf * 128 +
                        ((ks * 64 + q * 16) ^ ((r & 7) << 4)));
            }
#pragma unroll
            for (int fm = 0; fm < 4; ++fm)
#pragma unroll
                for (int fn = 0; fn < 4; ++fn)
                    acc[fm][fn] = __builtin_amdgcn_mfma_f32_16x16x32_bf16(
                        af[fm], bfv[fn], acc[fm][fn], 0, 0, 0);
        }
        cur ^= 1;
    }

    // Epilogue. C/D layout: col(n) = lane&15, row(m) = q*4 + reg.
    float psum[4][4];
    const float* wfb = wfull + n0 + wn * 64;
#pragma unroll
    for (int fm = 0; fm < 4; ++fm) {
#pragma unroll
        for (int i = 0; i < 4; ++i) {
            const int row_g = m0 + wm * 64 + fm * 16 + q * 4 + i;
            const unsigned bidx = (unsigned)row_g / 196u;
            const float* a2 = att2p + (size_t)bidx * A_ + n0 + wn * 64;
            float s = 0.f;
#pragma unroll
            for (int fn = 0; fn < 4; ++fn) {
                const int cl = fn * 16 + r;
                float v = acc[fm][fn][i] + a2[cl];
                v = fmaxf(v, 0.f);
                s += v * wfb[cl];
            }
            psum[fm][i] = s;
        }
    }
#pragma unroll
    for (int fm = 0; fm < 4; ++fm)
#pragma unroll
        for (int i = 0; i < 4; ++i) {
            float v = psum[fm][i];
            v += __shfl_xor(v, 1);
            v += __shfl_xor(v, 2);
            v += __shfl_xor(v, 4);
            v += __shfl_xor(v, 8);
            if (r == 0) red[wn][wm * 64 + fm * 16 + q * 4 + i] = v;
        }
    __syncthreads();
    if (t < 128) atomicAdd(&scores[m0 + t], red[0][t] + red[1][t]);
}

// ---------------------------------------------------------------------------
// K3: softmax over P=196 per batch; alpha (fp32) -> d_out elems [262144,...).
// ---------------------------------------------------------------------------
__global__ __launch_bounds__(256) void k_softmax(
    const float* __restrict__ scores, float* __restrict__ out) {
    const int b = blockIdx.x;
    const int t = threadIdx.x;
    __shared__ float sm[256];
    const bool act = t < P_;
    const float val = act ? scores[b * P_ + t] : 0.f;
    sm[t] = act ? val : -1e30f;
    __syncthreads();
    for (int off = 128; off > 0; off >>= 1) {
        if (t < off) sm[t] = fmaxf(sm[t], sm[t + off]);
        __syncthreads();
    }
    const float mx = sm[0];
    __syncthreads();
    const float e = act ? __expf(val - mx) : 0.f;
    sm[t] = e;
    __syncthreads();
    for (int off = 128; off > 0; off >>= 1) {
        if (t < off) sm[t] = sm[t] + sm[t + off];
        __syncthreads();
    }
    const float inv = 1.0f / sm[0];
    if (act) out[(size_t)B_ * E_ + b * P_ + t] = e * inv;
}

// ---------------------------------------------------------------------------
// K4: context[b][e] = sum_p alpha[b][p] * enc[b][p][e]  (all fp32)
// unroll 14 (196 = 14*14) for memory-level parallelism.
// ---------------------------------------------------------------------------
__global__ __launch_bounds__(256) void k_context(
    const float* __restrict__ enc, float* __restrict__ out) {
    const int b = blockIdx.y;
    const int e0 = blockIdx.x * 1024 + threadIdx.x * 4;
    __shared__ float al[P_];
    if (threadIdx.x < P_)
        al[threadIdx.x] = out[(size_t)B_ * E_ + b * P_ + threadIdx.x];
    __syncthreads();
    float ax = 0.f, ay = 0.f, az = 0.f, aw = 0.f;
    const float* base = enc + (size_t)b * P_ * E_ + e0;
#pragma unroll 14
    for (int p = 0; p < P_; ++p) {
        const float4 v = *(const float4*)(base + (size_t)p * E_);
        const float ap = al[p];
        ax += ap * v.x; ay += ap * v.y; az += ap * v.z; aw += ap * v.w;
    }
    float4 sv; sv.x = ax; sv.y = ay; sv.z = az; sv.w = aw;
    *(float4*)(out + (size_t)b * E_ + e0) = sv;
}

// ---------------------------------------------------------------------------
extern "C" void kernel_launch(void* const* d_in, const int* in_sizes, int n_in,
                              void* d_out, int out_size, void* d_ws,
                              size_t ws_size, hipStream_t stream) {
    const float* enc   = (const float*)d_in[0];
    const float* dh    = (const float*)d_in[1];
    const float* wenc  = (const float*)d_in[2];
    const float* benc  = (const float*)d_in[3];
    const float* wdec  = (const float*)d_in[4];
    const float* bdec  = (const float*)d_in[5];
    const float* wfull = (const float*)d_in[6];
    // d_in[7] = b_full: softmax shift-invariant, unused
    float* out = (float*)d_out;

    float* att2p  = out;                              // bytes [0, 524288)
    float* scores = (float*)((char*)d_out + 524288);  // bytes [524288, 624640)

    k_cvt<<<2048, 256, 0, stream>>>(enc);
    k_wt<<<dim3(A_ / 64, E_ / 64), 256, 0, stream>>>(wenc);
    k_att2<<<dim3(8, 16), 256, 0, stream>>>(dh, wdec, benc, bdec, scores,
                                            att2p);
    k_gemm_scores<<<dim3(8, M_ / 128), 256, 0, stream>>>(att2p, wfull,
                                                         scores);
    k_softmax<<<B_, 256, 0, stream>>>(scores, out);
    k_context<<<dim3(2, B_), 256, 0, stream>>>(enc, out);
}

// Round 4
// 566.997 us; speedup vs baseline: 1.0502x; 1.0502x over previous
//
#include <hip/hip_runtime.h>
#include <hip/hip_bf16.h>

// Show-Attend-Tell attention. B=128, P=196, E=2048, H=1024, A=1024.
// fp32 in / fp32 out (established round 6; passed absmax 1.95e-3).
// Round 11:
//   - k_pre merges cvt(enc->bf16) + wt(W_enc transpose->bf16) + att2 into
//     ONE 2048-block kernel: BW-bound cvt blocks hide the latency-bound
//     att2/wt blocks; 2 fewer launches.
//   - k_context reads g_enc (bf16, 103 MB, L3-warm) instead of fp32 enc
//     (205 MB); re-grid to 512 blocks (2/CU) from 256 (1/CU).
//   - GEMM unchanged from round 10 (195 us; next round: 8-phase port).
// Intermediates inside d_out (fp32, 287232 elems total):
//   bytes [0      : 524288)  att2' fp32 [B][A]   (dead after GEMM)
//   bytes [524288 : 624640)  scores fp32 [M]     (dead after softmax)
//   elems [262144 : 287232)  alpha fp32 (final)
//   elems [0      : 262144)  context fp32 (final, written LAST by k_context)

#define B_   128
#define P_   196
#define E_   2048
#define H_   1024
#define A_   1024
#define M_   (B_ * P_)      // 25088
#define NKSTEP (E_ / 64)    // 32

typedef __bf16 bf16x8 __attribute__((ext_vector_type(8)));
typedef float f32x4 __attribute__((ext_vector_type(4)));

// One-time converted operands (module globals):
__device__ __bf16 g_wt[(size_t)A_ * E_];    // 4 MB:  Wt[a][e] = bf16 W_enc[e][a]
__device__ __bf16 g_enc[(size_t)M_ * E_];   // 103 MB: bf16 enc[m][e]

__device__ __forceinline__ bf16x8 cvt8r(const float4 a, const float4 b) {
    bf16x8 r;
    r[0] = (__bf16)a.x; r[1] = (__bf16)a.y; r[2] = (__bf16)a.z; r[3] = (__bf16)a.w;
    r[4] = (__bf16)b.x; r[5] = (__bf16)b.y; r[6] = (__bf16)b.z; r[7] = (__bf16)b.w;
    return r;
}

// async 16B global->LDS (lds dest wave-uniform; HW adds lane*16)
__device__ __forceinline__ void gl16(const void* g, void* l) {
    __builtin_amdgcn_global_load_lds(
        (const __attribute__((address_space(1))) unsigned int*)g,
        (__attribute__((address_space(3))) unsigned int*)l, 16, 0, 0);
}

// ---------------------------------------------------------------------------
// K1: merged preprocessing. Grid 2048 x 256:
//   blocks [0,1792):    g_enc = bf16(enc), grid-stride (exactly 14 sweeps)
//   blocks [1792,1920): Wt[a][e] = bf16(W_enc[e][a]), 4 64x64 tiles each
//   blocks [1920,2048): zero scores; att2p[b][a] = benc+bdec+dh[b]@W_dec[:,a]
// All three run concurrently: cvt saturates HBM, att2/wt hide under it.
// ---------------------------------------------------------------------------
__global__ __launch_bounds__(256) void k_pre(
    const float* __restrict__ enc, const float* __restrict__ w,
    const float* __restrict__ dh, const float* __restrict__ wdec,
    const float* __restrict__ benc, const float* __restrict__ bdec,
    float* __restrict__ scores, float* __restrict__ att2p) {
    __shared__ float smem[10240];   // 40 KB scratch, per-branch layout
    const int bid = blockIdx.x;
    const int t = threadIdx.x;

    if (bid < 1792) {               // ---- cvt: enc -> g_enc (bf16) ----
        size_t i = ((size_t)bid * 256 + t) * 8;
        const size_t stride = (size_t)1792 * 256 * 8;   // covers n in 14 steps
#pragma unroll
        for (int it = 0; it < 14; ++it, i += stride) {
            const float4 a = *(const float4*)(enc + i);
            const float4 b = *(const float4*)(enc + i + 4);
            *(bf16x8*)&g_enc[i] = cvt8r(a, b);
        }
    } else if (bid < 1920) {        // ---- wt: W_enc^T -> g_wt (bf16) ----
        __bf16* tile = (__bf16*)smem;           // [64][72]
        const int er = t >> 2, c0 = (t & 3) * 16;
        const int ar = t >> 2, es0 = (t & 3) * 16;
#pragma unroll 1
        for (int j = 0; j < 4; ++j) {
            const int job = (bid - 1792) * 4 + j;       // 0..511
            const int a0 = (job & 15) * 64, e0 = (job >> 4) * 64;
            __syncthreads();        // tile reuse across jobs
#pragma unroll
            for (int jj = 0; jj < 4; ++jj) {
                const float4 v = *(const float4*)&w[(size_t)(e0 + er) * A_ +
                                                    a0 + c0 + jj * 4];
                tile[(c0 + jj * 4 + 0) * 72 + er] = (__bf16)v.x;
                tile[(c0 + jj * 4 + 1) * 72 + er] = (__bf16)v.y;
                tile[(c0 + jj * 4 + 2) * 72 + er] = (__bf16)v.z;
                tile[(c0 + jj * 4 + 3) * 72 + er] = (__bf16)v.w;
            }
            __syncthreads();
            *(bf16x8*)&g_wt[(size_t)(a0 + ar) * E_ + e0 + es0] =
                *(const bf16x8*)&tile[ar * 72 + es0];
            *(bf16x8*)&g_wt[(size_t)(a0 + ar) * E_ + e0 + es0 + 8] =
                *(const bf16x8*)&tile[ar * 72 + es0 + 8];
        }
    } else {                        // ---- att2 (+ zero scores) ----
        const int vbid = bid - 1920;            // 0..127
        const int a0 = (vbid & 7) * 128;
        const int b0 = (vbid >> 3) * 8;
        const int gi = vbid * 256 + t;
        if (gi < M_) scores[gi] = 0.f;          // zero before GEMM atomicAdd
        float (*hs)[H_] = (float (*)[H_])smem;          // [8][1024] 32 KB
        float (*red)[8] = (float (*)[8])(smem + 8192);  // [256][8]    8 KB
        for (int i = t; i < 8 * H_; i += 256)
            hs[i >> 10][i & 1023] =
                dh[(size_t)(b0 + (i >> 10)) * H_ + (i & 1023)];
        __syncthreads();
        const int a = a0 + (t & 127);
        const int h0 = (t >> 7) * 512;
        float acc[8] = {};
#pragma unroll 4
        for (int h = 0; h < 512; ++h) {
            const float wv = wdec[(size_t)(h0 + h) * A_ + a];
#pragma unroll
            for (int j = 0; j < 8; ++j) acc[j] += hs[j][h0 + h] * wv;
        }
#pragma unroll
        for (int j = 0; j < 8; ++j) red[t][j] = acc[j];
        __syncthreads();
        if (t < 128) {
            const float bb = benc[a0 + t] + bdec[a0 + t];
#pragma unroll
            for (int j = 0; j < 8; ++j)
                att2p[(size_t)(b0 + j) * A_ + a0 + t] =
                    red[t][j] + red[t + 128][j] + bb;
        }
    }
}

// ---------------------------------------------------------------------------
// K2: fused GEMM(att1, bf16 MFMA) + bias + relu + W_full row-reduce ->
// atomicAdd into scores[M]. C-tile 128m x 128n, BK=64, dbuf LDS.
// 4 waves: wm=wave>>1, wn=wave&1; each wave 64x64 via 4x4 frags 16x16x32.
// Both A and B tiles: global_load_lds direct, LDS linear [128 rows][64 k]
// bf16 (128 B/row); global SOURCE carries the inverse XOR-chunk swizzle:
//   LDS[row][chunk] (16B chunks) holds source chunk (chunk ^ (row&7)).
// Frag read: byte = row*128 + ((ks*64+q*16) ^ ((r&7)<<4)) -> conflict-free.
// One raw s_barrier per K-step preceded by vmcnt(0)+lgkmcnt(0).
// XCD swizzle: L = (orig&7)*196 + orig/8 (bijective, nwg=1568=8*196).
// (unchanged from round 10: 195 us, MfmaUtil 23%, bank-conflict 0)
// ---------------------------------------------------------------------------
__global__ __launch_bounds__(256, 2) void k_gemm_scores(
    const float* __restrict__ att2p,    // [B_][A_] fp32
    const float* __restrict__ wfull,    // [A_] fp32
    float* __restrict__ scores) {       // [M_] fp32
    __shared__ __align__(16) __bf16 As[2][128 * 64];
    __shared__ __align__(16) __bf16 Bs[2][128 * 64];
    __shared__ float red[2][128];

    const int t = threadIdx.x;
    const int lane = t & 63;
    const int wave = t >> 6;
    const int wm = wave >> 1, wn = wave & 1;
    const int q = lane >> 4, r = lane & 15;
    const int orig = blockIdx.y * 8 + blockIdx.x;      // 0..1567
    const int L = (orig & 7) * (M_ / 128) + (orig >> 3);
    const int bn = L & 7, bm = L >> 3;
    const int m0 = bm * 128, n0 = bn * 128;

    // staging addresses (bytes). row stride of both g_enc and g_wt = 4096 B.
    const int rbase = wave * 8 + (lane >> 3);            // 0..31
    const int cx = ((t & 7) ^ ((t >> 3) & 7)) * 16;      // swizzled chunk
    const char* pa = (const char*)g_enc + (size_t)(m0 + rbase) * 4096 + cx;
    const char* pb = (const char*)g_wt  + (size_t)(n0 + rbase) * 4096 + cx;
    char* ad0 = (char*)&As[0][0] + wave * 1024;
    char* ad1 = (char*)&As[1][0] + wave * 1024;
    char* bd0 = (char*)&Bs[0][0] + wave * 1024;
    char* bd1 = (char*)&Bs[1][0] + wave * 1024;

    f32x4 acc[4][4] = {};

    // ---- prologue: stage tile 0 into buffer 0 ----
#pragma unroll
    for (int i = 0; i < 4; ++i)
        gl16(pa + (size_t)i * 131072, ad0 + i * 4096);
#pragma unroll
    for (int i = 0; i < 4; ++i)
        gl16(pb + (size_t)i * 131072, bd0 + i * 4096);

    int cur = 0;
    for (int kt = 0; kt < NKSTEP; ++kt) {
        // buf[cur] ready once our own outstanding ops drain + all waves sync
        asm volatile("s_waitcnt vmcnt(0)" ::: "memory");
        asm volatile("s_waitcnt lgkmcnt(0)" ::: "memory");
        __builtin_amdgcn_s_barrier();

        const char* AsC = (const char*)&As[cur][0];
        const char* BsC = (const char*)&Bs[cur][0];

        if (kt + 1 < NKSTEP) {  // stage tile kt+1 into the other buffer
            char* ad = cur ? ad0 : ad1;
            char* bd = cur ? bd0 : bd1;
            const size_t ko = (size_t)(kt + 1) * 128;
#pragma unroll
            for (int i = 0; i < 4; ++i)
                gl16(pa + (size_t)i * 131072 + ko, ad + i * 4096);
#pragma unroll
            for (int i = 0; i < 4; ++i)
                gl16(pb + (size_t)i * 131072 + ko, bd + i * 4096);
        }

        // compute tile kt (plain C++: compiler handles lgkm waits)
#pragma unroll
        for (int ks = 0; ks < 2; ++ks) {
            bf16x8 af[4], bfv[4];
#pragma unroll
            for (int f = 0; f < 4; ++f) {
                const int mf = wm * 64 + f * 16 + r;      // mf&7 == r&7
                af[f] = *(const bf16x8*)(AsC + mf * 128 +
                        ((ks * 64 + q * 16) ^ ((r & 7) << 4)));
            }
#pragma unroll
            for (int f = 0; f < 4; ++f) {
                const int nf = wn * 64 + f * 16 + r;      // nf&7 == r&7
                bfv[f] = *(const bf16x8*)(BsC + nf * 128 +
                        ((ks * 64 + q * 16) ^ ((r & 7) << 4)));
            }
#pragma unroll
            for (int fm = 0; fm < 4; ++fm)
#pragma unroll
                for (int fn = 0; fn < 4; ++fn)
                    acc[fm][fn] = __builtin_amdgcn_mfma_f32_16x16x32_bf16(
                        af[fm], bfv[fn], acc[fm][fn], 0, 0, 0);
        }
        cur ^= 1;
    }

    // Epilogue. C/D layout: col(n) = lane&15, row(m) = q*4 + reg.
    float psum[4][4];
    const float* wfb = wfull + n0 + wn * 64;
#pragma unroll
    for (int fm = 0; fm < 4; ++fm) {
#pragma unroll
        for (int i = 0; i < 4; ++i) {
            const int row_g = m0 + wm * 64 + fm * 16 + q * 4 + i;
            const unsigned bidx = (unsigned)row_g / 196u;
            const float* a2 = att2p + (size_t)bidx * A_ + n0 + wn * 64;
            float s = 0.f;
#pragma unroll
            for (int fn = 0; fn < 4; ++fn) {
                const int cl = fn * 16 + r;
                float v = acc[fm][fn][i] + a2[cl];
                v = fmaxf(v, 0.f);
                s += v * wfb[cl];
            }
            psum[fm][i] = s;
        }
    }
#pragma unroll
    for (int fm = 0; fm < 4; ++fm)
#pragma unroll
        for (int i = 0; i < 4; ++i) {
            float v = psum[fm][i];
            v += __shfl_xor(v, 1);
            v += __shfl_xor(v, 2);
            v += __shfl_xor(v, 4);
            v += __shfl_xor(v, 8);
            if (r == 0) red[wn][wm * 64 + fm * 16 + q * 4 + i] = v;
        }
    __syncthreads();
    if (t < 128) atomicAdd(&scores[m0 + t], red[0][t] + red[1][t]);
}

// ---------------------------------------------------------------------------
// K3: softmax over P=196 per batch; alpha (fp32) -> d_out elems [262144,...).
// ---------------------------------------------------------------------------
__global__ __launch_bounds__(256) void k_softmax(
    const float* __restrict__ scores, float* __restrict__ out) {
    const int b = blockIdx.x;
    const int t = threadIdx.x;
    __shared__ float sm[256];
    const bool act = t < P_;
    const float val = act ? scores[b * P_ + t] : 0.f;
    sm[t] = act ? val : -1e30f;
    __syncthreads();
    for (int off = 128; off > 0; off >>= 1) {
        if (t < off) sm[t] = fmaxf(sm[t], sm[t + off]);
        __syncthreads();
    }
    const float mx = sm[0];
    __syncthreads();
    const float e = act ? __expf(val - mx) : 0.f;
    sm[t] = e;
    __syncthreads();
    for (int off = 128; off > 0; off >>= 1) {
        if (t < off) sm[t] = sm[t] + sm[t + off];
        __syncthreads();
    }
    const float inv = 1.0f / sm[0];
    if (act) out[(size_t)B_ * E_ + b * P_ + t] = e * inv;
}

// ---------------------------------------------------------------------------
// K4: context[b][e] = sum_p alpha[b][p] * g_enc[b][p][e]  (bf16 enc, fp32 acc)
// Grid (4 e-chunks of 512, 128 b) = 512 blocks (2/CU). Thread: 2 e-cols
// via one uint (bf16x2) per p; bf16->f32 = bit shift. unroll 14.
// ---------------------------------------------------------------------------
__global__ __launch_bounds__(256) void k_context(float* __restrict__ out) {
    const int b = blockIdx.y;
    const int e0 = blockIdx.x * 512 + threadIdx.x * 2;
    __shared__ float al[P_];
    if (threadIdx.x < P_)
        al[threadIdx.x] = out[(size_t)B_ * E_ + b * P_ + threadIdx.x];
    __syncthreads();
    float ax = 0.f, ay = 0.f;
    const char* base = (const char*)g_enc +
                       ((size_t)b * P_) * (E_ * 2) + (size_t)e0 * 2;
#pragma unroll 14
    for (int p = 0; p < P_; ++p) {
        const unsigned u = *(const unsigned*)(base + (size_t)p * (E_ * 2));
        const float ap = al[p];
        ax += ap * __uint_as_float(u << 16);
        ay += ap * __uint_as_float(u & 0xffff0000u);
    }
    float2 sv; sv.x = ax; sv.y = ay;
    *(float2*)(out + (size_t)b * E_ + e0) = sv;
}

// ---------------------------------------------------------------------------
extern "C" void kernel_launch(void* const* d_in, const int* in_sizes, int n_in,
                              void* d_out, int out_size, void* d_ws,
                              size_t ws_size, hipStream_t stream) {
    const float* enc   = (const float*)d_in[0];
    const float* dh    = (const float*)d_in[1];
    const float* wenc  = (const float*)d_in[2];
    const float* benc  = (const float*)d_in[3];
    const float* wdec  = (const float*)d_in[4];
    const float* bdec  = (const float*)d_in[5];
    const float* wfull = (const float*)d_in[6];
    // d_in[7] = b_full: softmax shift-invariant, unused
    float* out = (float*)d_out;

    float* att2p  = out;                              // bytes [0, 524288)
    float* scores = (float*)((char*)d_out + 524288);  // bytes [524288, 624640)

    k_pre<<<2048, 256, 0, stream>>>(enc, wenc, dh, wdec, benc, bdec, scores,
                                    att2p);
    k_gemm_scores<<<dim3(8, M_ / 128), 256, 0, stream>>>(att2p, wfull,
                                                         scores);
    k_softmax<<<B_, 256, 0, stream>>>(scores, out);
    k_context<<<dim3(4, 128), 256, 0, stream>>>(out);
}

// Round 5
// 527.751 us; speedup vs baseline: 1.1283x; 1.0744x over previous
//
#include <hip/hip_runtime.h>
#include <hip/hip_bf16.h>

// Show-Attend-Tell attention. B=128, P=196, E=2048, H=1024, A=1024.
// fp32 in / fp32 out (established round 6; passed absmax 1.95e-3).
// Round 12: GEMM ported to the 8-phase counted-vmcnt schedule (T3+T4+T5):
//   256x256 tile, BK=64, 8 waves (2m x 4n) of 128x64 output each.
//   LDS 128 KB: [2 K-tile slots][2 quadrant-halves][subgroups] per operand.
//   Halves are QUADRANT-aligned (A-half mh = rows {wm*128+mh*64..} for both
//   wm; B-half nh = cols {wn*64+nh*32..} for all wn), so each half's last
//   read is mid-K-tile and staging 1 half-tile/phase never collides:
//     phase:  p0      p1      p2        p3        p4        p5        p6        p7
//     reads:  A0,B0   B1      A1        -         A0,B0     B1        A1        -
//     (slot)  ka      ka      ka        ka        kb        kb        kb        kb
//     stage:  A1(kb)  B1(kb)  A0(ka+2)  B0(ka+2)  A1(ka+2)  B1(ka+2)  A0(kb+2)  B0(kb+2)
//     wait:   -       -       -         vmcnt(4)  -         -         -         vmcnt(4)
//   vmcnt(4) = 2 half-tiles (4 gl16) in flight, never drains to 0 in loop.
//   Death check (slot overwritten by stage at phase p had last read <= p-2's
//   MFMA, published by the two barriers in between). Tail iter peeled with
//   vmcnt(0). sched_barrier(0) before every s_barrier pins phase contents.
// Intermediates inside d_out (fp32, 287232 elems total):
//   bytes [0      : 524288)  att2' fp32 [B][A]   (dead after GEMM)
//   bytes [524288 : 624640)  scores fp32 [M]     (dead after softmax)
//   elems [262144 : 287232)  alpha fp32 (final)
//   elems [0      : 262144)  context fp32 (final, written LAST by k_context)

#define B_   128
#define P_   196
#define E_   2048
#define H_   1024
#define A_   1024
#define M_   (B_ * P_)      // 25088
#define NKSTEP (E_ / 64)    // 32

typedef __bf16 bf16x8 __attribute__((ext_vector_type(8)));
typedef float f32x4 __attribute__((ext_vector_type(4)));

// One-time converted operands (module globals):
__device__ __bf16 g_wt[(size_t)A_ * E_];    // 4 MB:  Wt[a][e] = bf16 W_enc[e][a]
__device__ __bf16 g_enc[(size_t)M_ * E_];   // 103 MB: bf16 enc[m][e]

__device__ __forceinline__ bf16x8 cvt8r(const float4 a, const float4 b) {
    bf16x8 r;
    r[0] = (__bf16)a.x; r[1] = (__bf16)a.y; r[2] = (__bf16)a.z; r[3] = (__bf16)a.w;
    r[4] = (__bf16)b.x; r[5] = (__bf16)b.y; r[6] = (__bf16)b.z; r[7] = (__bf16)b.w;
    return r;
}

// async 16B global->LDS (lds dest wave-uniform; HW adds lane*16)
__device__ __forceinline__ void gl16(const void* g, void* l) {
    __builtin_amdgcn_global_load_lds(
        (const __attribute__((address_space(1))) unsigned int*)g,
        (__attribute__((address_space(3))) unsigned int*)l, 16, 0, 0);
}

// ---------------------------------------------------------------------------
// K1: merged preprocessing. Grid 2048 x 256:
//   blocks [0,1792):    g_enc = bf16(enc), grid-stride (exactly 14 sweeps)
//   blocks [1792,1920): Wt[a][e] = bf16(W_enc[e][a]), 4 64x64 tiles each
//   blocks [1920,2048): zero scores; att2p[b][a] = benc+bdec+dh[b]@W_dec[:,a]
// ---------------------------------------------------------------------------
__global__ __launch_bounds__(256) void k_pre(
    const float* __restrict__ enc, const float* __restrict__ w,
    const float* __restrict__ dh, const float* __restrict__ wdec,
    const float* __restrict__ benc, const float* __restrict__ bdec,
    float* __restrict__ scores, float* __restrict__ att2p) {
    __shared__ float smem[10240];   // 40 KB scratch, per-branch layout
    const int bid = blockIdx.x;
    const int t = threadIdx.x;

    if (bid < 1792) {               // ---- cvt: enc -> g_enc (bf16) ----
        size_t i = ((size_t)bid * 256 + t) * 8;
        const size_t stride = (size_t)1792 * 256 * 8;   // covers n in 14 steps
#pragma unroll
        for (int it = 0; it < 14; ++it, i += stride) {
            const float4 a = *(const float4*)(enc + i);
            const float4 b = *(const float4*)(enc + i + 4);
            *(bf16x8*)&g_enc[i] = cvt8r(a, b);
        }
    } else if (bid < 1920) {        // ---- wt: W_enc^T -> g_wt (bf16) ----
        __bf16* tile = (__bf16*)smem;           // [64][72]
        const int er = t >> 2, c0 = (t & 3) * 16;
        const int ar = t >> 2, es0 = (t & 3) * 16;
#pragma unroll 1
        for (int j = 0; j < 4; ++j) {
            const int job = (bid - 1792) * 4 + j;       // 0..511
            const int a0 = (job & 15) * 64, e0 = (job >> 4) * 64;
            __syncthreads();        // tile reuse across jobs
#pragma unroll
            for (int jj = 0; jj < 4; ++jj) {
                const float4 v = *(const float4*)&w[(size_t)(e0 + er) * A_ +
                                                    a0 + c0 + jj * 4];
                tile[(c0 + jj * 4 + 0) * 72 + er] = (__bf16)v.x;
                tile[(c0 + jj * 4 + 1) * 72 + er] = (__bf16)v.y;
                tile[(c0 + jj * 4 + 2) * 72 + er] = (__bf16)v.z;
                tile[(c0 + jj * 4 + 3) * 72 + er] = (__bf16)v.w;
            }
            __syncthreads();
            *(bf16x8*)&g_wt[(size_t)(a0 + ar) * E_ + e0 + es0] =
                *(const bf16x8*)&tile[ar * 72 + es0];
            *(bf16x8*)&g_wt[(size_t)(a0 + ar) * E_ + e0 + es0 + 8] =
                *(const bf16x8*)&tile[ar * 72 + es0 + 8];
        }
    } else {                        // ---- att2 (+ zero scores) ----
        const int vbid = bid - 1920;            // 0..127
        const int a0 = (vbid & 7) * 128;
        const int b0 = (vbid >> 3) * 8;
        const int gi = vbid * 256 + t;
        if (gi < M_) scores[gi] = 0.f;          // zero before GEMM atomicAdd
        float (*hs)[H_] = (float (*)[H_])smem;          // [8][1024] 32 KB
        float (*red)[8] = (float (*)[8])(smem + 8192);  // [256][8]    8 KB
        for (int i = t; i < 8 * H_; i += 256)
            hs[i >> 10][i & 1023] =
                dh[(size_t)(b0 + (i >> 10)) * H_ + (i & 1023)];
        __syncthreads();
        const int a = a0 + (t & 127);
        const int h0 = (t >> 7) * 512;
        float acc[8] = {};
#pragma unroll 4
        for (int h = 0; h < 512; ++h) {
            const float wv = wdec[(size_t)(h0 + h) * A_ + a];
#pragma unroll
            for (int j = 0; j < 8; ++j) acc[j] += hs[j][h0 + h] * wv;
        }
#pragma unroll
        for (int j = 0; j < 8; ++j) red[t][j] = acc[j];
        __syncthreads();
        if (t < 128) {
            const float bb = benc[a0 + t] + bdec[a0 + t];
#pragma unroll
            for (int j = 0; j < 8; ++j)
                att2p[(size_t)(b0 + j) * A_ + a0 + t] =
                    red[t][j] + red[t + 128][j] + bb;
        }
    }
}

// ---------------------------------------------------------------------------
// K2: fused GEMM + bias + relu + W_full row-reduce -> atomicAdd scores[M].
// 8-phase schedule, 256x256 tile, BK=64, 8 waves (wm=w>>2, wn=w&3), each
// wave outputs 128x64 (8 m-frags x 4 n-frags of 16x16x32 bf16).
// LDS A: [slot2][half2][sg2][row64][128B]  (sg=wm; half mh = 64-row groups)
// LDS B: [slot2][half2][sg4][row32][128B]  (sg=wn; half nh = 32-col groups)
// Staged via global_load_lds, source pre-swizzled: LDS chunk c of row rr
// holds source chunk c ^ (rr&7); frag read XORs it back -> conflict-free.
// XCD swizzle: nwg=392=8*49, L=(orig&7)*49+orig>>3, bn=L&3, bm=L>>2.
// ---------------------------------------------------------------------------
__global__ __launch_bounds__(512, 1) void k_gemm_scores(
    const float* __restrict__ att2p,    // [B_][A_] fp32
    const float* __restrict__ wfull,    // [A_] fp32
    float* __restrict__ scores) {       // [M_] fp32
    __shared__ __align__(16) __bf16 As[2][2][2][64][64];    // 64 KB
    __shared__ __align__(16) __bf16 Bs[2][2][4][32][64];    // 64 KB

    const int t = threadIdx.x;
    const int lane = t & 63, w = t >> 6;
    const int wm = w >> 2, wn = w & 3;
    const int q = lane >> 4, r = lane & 15;
    const int orig = blockIdx.x;                 // 0..391
    const int L = (orig & 7) * 49 + (orig >> 3); // bijective (392 = 8*49)
    const int bn = L & 3, bm = L >> 2;
    const int m0 = bm * 256, n0 = bn * 256;

    // staging source bases (row stride 4096 B in both g_enc and g_wt)
    const int swz = ((t & 7) ^ ((t >> 3) & 7)) * 16;
    const char* gA = (const char*)g_enc + (size_t)(m0 + (t >> 3)) * 4096 + swz;
    const char* gB = (const char*)g_wt +
        (size_t)(n0 + (t >> 8) * 64 + ((t >> 3) & 31)) * 4096 + swz;

    const int kx0 = (q * 16) ^ ((r & 7) << 4);
    const int kx1 = (64 + q * 16) ^ ((r & 7) << 4);

    bf16x8 af[4][2], bf0[2][2], bf1[2][2];
    f32x4 acc[8][4] = {};

// stage one half-tile (2 x gl16 per wave); kt = K-tile index
#define STG_A(slot, h, kt) do { \
    gl16(gA + ((size_t)(h) * 64) * 4096 + (size_t)(kt) * 128, \
         (char*)As + (slot) * 32768 + (h) * 16384 + w * 1024); \
    gl16(gA + ((size_t)(h) * 64 + 128) * 4096 + (size_t)(kt) * 128, \
         (char*)As + (slot) * 32768 + (h) * 16384 + 8192 + w * 1024); } while (0)
#define STG_B(slot, h, kt) do { \
    gl16(gB + ((size_t)(h) * 32) * 4096 + (size_t)(kt) * 128, \
         (char*)Bs + (slot) * 32768 + (h) * 16384 + w * 1024); \
    gl16(gB + ((size_t)(h) * 32 + 128) * 4096 + (size_t)(kt) * 128, \
         (char*)Bs + (slot) * 32768 + (h) * 16384 + 8192 + w * 1024); } while (0)

#define RD_A(slot, mh) do { \
    _Pragma("unroll") \
    for (int fl = 0; fl < 4; ++fl) { \
        const char* p_ = (const char*)As + (slot) * 32768 + (mh) * 16384 + \
                         wm * 8192 + (fl * 16 + r) * 128; \
        af[fl][0] = *(const bf16x8*)(p_ + kx0); \
        af[fl][1] = *(const bf16x8*)(p_ + kx1); } } while (0)
#define RD_B(slot, nh, B) do { \
    _Pragma("unroll") \
    for (int nl = 0; nl < 2; ++nl) { \
        const char* p_ = (const char*)Bs + (slot) * 32768 + (nh) * 16384 + \
                         wn * 4096 + (nl * 16 + r) * 128; \
        B[nl][0] = *(const bf16x8*)(p_ + kx0); \
        B[nl][1] = *(const bf16x8*)(p_ + kx1); } } while (0)
#define MM16(MH, NH, B) do { \
    _Pragma("unroll") \
    for (int fl = 0; fl < 4; ++fl) { \
        _Pragma("unroll") \
        for (int nl = 0; nl < 2; ++nl) { \
            acc[(MH)*4+fl][(NH)*2+nl] = __builtin_amdgcn_mfma_f32_16x16x32_bf16( \
                af[fl][0], B[nl][0], acc[(MH)*4+fl][(NH)*2+nl], 0, 0, 0); \
            acc[(MH)*4+fl][(NH)*2+nl] = __builtin_amdgcn_mfma_f32_16x16x32_bf16( \
                af[fl][1], B[nl][1], acc[(MH)*4+fl][(NH)*2+nl], 0, 0, 0); } } } while (0)
#define BAR() do { __builtin_amdgcn_sched_barrier(0); \
                   __builtin_amdgcn_s_barrier(); } while (0)
#define PRIO_MM(MH, NH, B) do { __builtin_amdgcn_s_setprio(1); \
    MM16(MH, NH, B); __builtin_amdgcn_s_setprio(0); } while (0)

    // ---- prologue: tile0 (all 4 halves) + tile1 (A0,B0); 12 gl16 ----
    STG_A(0, 0, 0); STG_B(0, 0, 0); STG_A(0, 1, 0); STG_B(0, 1, 0);
    STG_A(1, 0, 1); STG_B(1, 0, 1);
    asm volatile("s_waitcnt vmcnt(4)" ::: "memory");    // tile0 landed
    BAR();

    for (int i = 0; i < 15; ++i) {
        const int kb = 2 * i + 1, ka2 = 2 * i + 2, kb2 = 2 * i + 3;
        // p0: compute ka quad(0,0); stage A1(kb)
        RD_A(0, 0); RD_B(0, 0, bf0); STG_A(1, 1, kb); BAR();
        PRIO_MM(0, 0, bf0); BAR();
        // p1: quad(0,1); stage B1(kb)
        RD_B(0, 1, bf1); STG_B(1, 1, kb); BAR();
        PRIO_MM(0, 1, bf1); BAR();
        // p2: quad(1,0); stage A0(ka+2)
        RD_A(0, 1); STG_A(0, 0, ka2); BAR();
        PRIO_MM(1, 0, bf0); BAR();
        // p3: quad(1,1); stage B0(ka+2); WAIT -> kb fully landed
        STG_B(0, 0, ka2);
        asm volatile("s_waitcnt vmcnt(4)" ::: "memory");
        BAR();
        PRIO_MM(1, 1, bf1); BAR();
        // p4: compute kb quad(0,0); stage A1(ka+2)
        RD_A(1, 0); RD_B(1, 0, bf0); STG_A(0, 1, ka2); BAR();
        PRIO_MM(0, 0, bf0); BAR();
        // p5: quad(0,1); stage B1(ka+2)
        RD_B(1, 1, bf1); STG_B(0, 1, ka2); BAR();
        PRIO_MM(0, 1, bf1); BAR();
        // p6: quad(1,0); stage A0(kb+2)
        RD_A(1, 1); STG_A(1, 0, kb2); BAR();
        PRIO_MM(1, 0, bf0); BAR();
        // p7: quad(1,1); stage B0(kb+2); WAIT -> ka+2 fully landed
        STG_B(1, 0, kb2);
        asm volatile("s_waitcnt vmcnt(4)" ::: "memory");
        BAR();
        PRIO_MM(1, 1, bf1); BAR();
    }
    // ---- peeled tail: ka=30, kb=31; only A1/B1(31) still to stage ----
    RD_A(0, 0); RD_B(0, 0, bf0); STG_A(1, 1, 31); BAR();
    PRIO_MM(0, 0, bf0); BAR();
    RD_B(0, 1, bf1); STG_B(1, 1, 31); BAR();
    PRIO_MM(0, 1, bf1); BAR();
    RD_A(0, 1); BAR();
    PRIO_MM(1, 0, bf0); BAR();
    asm volatile("s_waitcnt vmcnt(0)" ::: "memory");    // tile31 landed
    BAR();
    PRIO_MM(1, 1, bf1); BAR();
    RD_A(1, 0); RD_B(1, 0, bf0); BAR();
    PRIO_MM(0, 0, bf0); BAR();
    RD_B(1, 1, bf1); BAR();
    PRIO_MM(0, 1, bf1); BAR();
    RD_A(1, 1); BAR();
    PRIO_MM(1, 0, bf0); BAR();
    BAR();
    PRIO_MM(1, 1, bf1); BAR();

    // ---- epilogue: bias+relu+wfull dot, reduce, atomicAdd ----
    // C/D: col(n) = r, row(m) = q*4+i. red overlays As (dead, 0 gl16 left).
    float* red = (float*)As;            // [256][4] floats
    const float* wfb = wfull + n0 + wn * 64;
#pragma unroll
    for (int f = 0; f < 8; ++f) {
#pragma unroll
        for (int i2 = 0; i2 < 4; ++i2) {
            const int row256 = wm * 128 + f * 16 + q * 4 + i2;
            const int row_g = m0 + row256;
            const unsigned bidx = (unsigned)row_g / 196u;
            const float* a2 = att2p + (size_t)bidx * A_ + n0 + wn * 64;
            float s = 0.f;
#pragma unroll
            for (int fn = 0; fn < 4; ++fn) {
                const int cl = fn * 16 + r;
                float v = acc[f][fn][i2] + a2[cl];
                v = fmaxf(v, 0.f);
                s += v * wfb[cl];
            }
            s += __shfl_xor(s, 1);
            s += __shfl_xor(s, 2);
            s += __shfl_xor(s, 4);
            s += __shfl_xor(s, 8);
            if (r == 0) red[row256 * 4 + wn] = s;
        }
    }
    __syncthreads();
    if (t < 256)
        atomicAdd(&scores[m0 + t],
                  red[t * 4] + red[t * 4 + 1] + red[t * 4 + 2] + red[t * 4 + 3]);
#undef STG_A
#undef STG_B
#undef RD_A
#undef RD_B
#undef MM16
#undef BAR
#undef PRIO_MM
}

// ---------------------------------------------------------------------------
// K3: softmax over P=196 per batch; alpha (fp32) -> d_out elems [262144,...).
// ---------------------------------------------------------------------------
__global__ __launch_bounds__(256) void k_softmax(
    const float* __restrict__ scores, float* __restrict__ out) {
    const int b = blockIdx.x;
    const int t = threadIdx.x;
    __shared__ float sm[256];
    const bool act = t < P_;
    const float val = act ? scores[b * P_ + t] : 0.f;
    sm[t] = act ? val : -1e30f;
    __syncthreads();
    for (int off = 128; off > 0; off >>= 1) {
        if (t < off) sm[t] = fmaxf(sm[t], sm[t + off]);
        __syncthreads();
    }
    const float mx = sm[0];
    __syncthreads();
    const float e = act ? __expf(val - mx) : 0.f;
    sm[t] = e;
    __syncthreads();
    for (int off = 128; off > 0; off >>= 1) {
        if (t < off) sm[t] = sm[t] + sm[t + off];
        __syncthreads();
    }
    const float inv = 1.0f / sm[0];
    if (act) out[(size_t)B_ * E_ + b * P_ + t] = e * inv;
}

// ---------------------------------------------------------------------------
// K4: context[b][e] = sum_p alpha[b][p] * g_enc[b][p][e]  (bf16 enc, fp32 acc)
// Grid (4 e-chunks of 512, 128 b) = 512 blocks (2/CU).
// ---------------------------------------------------------------------------
__global__ __launch_bounds__(256) void k_context(float* __restrict__ out) {
    const int b = blockIdx.y;
    const int e0 = blockIdx.x * 512 + threadIdx.x * 2;
    __shared__ float al[P_];
    if (threadIdx.x < P_)
        al[threadIdx.x] = out[(size_t)B_ * E_ + b * P_ + threadIdx.x];
    __syncthreads();
    float ax = 0.f, ay = 0.f;
    const char* base = (const char*)g_enc +
                       ((size_t)b * P_) * (E_ * 2) + (size_t)e0 * 2;
#pragma unroll 14
    for (int p = 0; p < P_; ++p) {
        const unsigned u = *(const unsigned*)(base + (size_t)p * (E_ * 2));
        const float ap = al[p];
        ax += ap * __uint_as_float(u << 16);
        ay += ap * __uint_as_float(u & 0xffff0000u);
    }
    float2 sv; sv.x = ax; sv.y = ay;
    *(float2*)(out + (size_t)b * E_ + e0) = sv;
}

// ---------------------------------------------------------------------------
extern "C" void kernel_launch(void* const* d_in, const int* in_sizes, int n_in,
                              void* d_out, int out_size, void* d_ws,
                              size_t ws_size, hipStream_t stream) {
    const float* enc   = (const float*)d_in[0];
    const float* dh    = (const float*)d_in[1];
    const float* wenc  = (const float*)d_in[2];
    const float* benc  = (const float*)d_in[3];
    const float* wdec  = (const float*)d_in[4];
    const float* bdec  = (const float*)d_in[5];
    const float* wfull = (const float*)d_in[6];
    // d_in[7] = b_full: softmax shift-invariant, unused
    float* out = (float*)d_out;

    float* att2p  = out;                              // bytes [0, 524288)
    float* scores = (float*)((char*)d_out + 524288);  // bytes [524288, 624640)

    k_pre<<<2048, 256, 0, stream>>>(enc, wenc, dh, wdec, benc, bdec, scores,
                                    att2p);
    k_gemm_scores<<<392, 512, 0, stream>>>(att2p, wfull, scores);
    k_softmax<<<B_, 256, 0, stream>>>(scores, out);
    k_context<<<dim3(4, B_), 256, 0, stream>>>(out);
}

// Round 6
// 512.477 us; speedup vs baseline: 1.1619x; 1.0298x over previous
//
#include <hip/hip_runtime.h>
#include <hip/hip_bf16.h>

// Show-Attend-Tell attention. B=128, P=196, E=2048, H=1024, A=1024.
// fp32 in / fp32 out (established round 6; passed absmax 1.95e-3).
// Round 13: k_pre branch REORDER (att2 blocks 0-127, wt 128-255, cvt rest).
//   Round-12 counters: k_pre 162 us @ 1.35 TB/s, VALU 4% -> dispatch tail:
//   cvt blocks (IDs 0-1791) filled the GPU first; the 128 latency-bound
//   att2 blocks (IDs 1920+) started only as cvt drained, then ran with
//   7/8 of the GPU idle. Putting att2/wt at the LOW block IDs hides them
//   entirely under the BW-bound cvt sweep.
// GEMM: 8-phase counted-vmcnt schedule (round 12; left top-5 at <162 us).
// Intermediates inside d_out (fp32, 287232 elems total):
//   bytes [0      : 524288)  att2' fp32 [B][A]   (dead after GEMM)
//   bytes [524288 : 624640)  scores fp32 [M]     (dead after softmax)
//   elems [262144 : 287232)  alpha fp32 (final)
//   elems [0      : 262144)  context fp32 (final, written LAST by k_context)

#define B_   128
#define P_   196
#define E_   2048
#define H_   1024
#define A_   1024
#define M_   (B_ * P_)      // 25088
#define NKSTEP (E_ / 64)    // 32

typedef __bf16 bf16x8 __attribute__((ext_vector_type(8)));
typedef float f32x4 __attribute__((ext_vector_type(4)));

// One-time converted operands (module globals):
__device__ __bf16 g_wt[(size_t)A_ * E_];    // 4 MB:  Wt[a][e] = bf16 W_enc[e][a]
__device__ __bf16 g_enc[(size_t)M_ * E_];   // 103 MB: bf16 enc[m][e]

__device__ __forceinline__ bf16x8 cvt8r(const float4 a, const float4 b) {
    bf16x8 r;
    r[0] = (__bf16)a.x; r[1] = (__bf16)a.y; r[2] = (__bf16)a.z; r[3] = (__bf16)a.w;
    r[4] = (__bf16)b.x; r[5] = (__bf16)b.y; r[6] = (__bf16)b.z; r[7] = (__bf16)b.w;
    return r;
}

// async 16B global->LDS (lds dest wave-uniform; HW adds lane*16)
__device__ __forceinline__ void gl16(const void* g, void* l) {
    __builtin_amdgcn_global_load_lds(
        (const __attribute__((address_space(1))) unsigned int*)g,
        (__attribute__((address_space(3))) unsigned int*)l, 16, 0, 0);
}

// ---------------------------------------------------------------------------
// K1: merged preprocessing. Grid 2048 x 256, LATENCY-BOUND BRANCHES FIRST:
//   blocks [0,128):     zero scores; att2p[b][a] = benc+bdec+dh[b]@W_dec[:,a]
//   blocks [128,256):   Wt[a][e] = bf16(W_enc[e][a]), 4 64x64 tiles each
//   blocks [256,2048):  g_enc = bf16(enc), grid-stride (exactly 14 sweeps)
// att2/wt start first and finish under the BW-bound cvt sweep (no tail).
// ---------------------------------------------------------------------------
__global__ __launch_bounds__(256) void k_pre(
    const float* __restrict__ enc, const float* __restrict__ w,
    const float* __restrict__ dh, const float* __restrict__ wdec,
    const float* __restrict__ benc, const float* __restrict__ bdec,
    float* __restrict__ scores, float* __restrict__ att2p) {
    __shared__ float smem[10240];   // 40 KB scratch, per-branch layout
    const int bid = blockIdx.x;
    const int t = threadIdx.x;

    if (bid < 128) {                // ---- att2 (+ zero scores) ----
        const int vbid = bid;                   // 0..127
        const int a0 = (vbid & 7) * 128;
        const int b0 = (vbid >> 3) * 8;
        const int gi = vbid * 256 + t;
        if (gi < M_) scores[gi] = 0.f;          // zero before GEMM atomicAdd
        float (*hs)[H_] = (float (*)[H_])smem;          // [8][1024] 32 KB
        float (*red)[8] = (float (*)[8])(smem + 8192);  // [256][8]    8 KB
        for (int i = t; i < 8 * H_; i += 256)
            hs[i >> 10][i & 1023] =
                dh[(size_t)(b0 + (i >> 10)) * H_ + (i & 1023)];
        __syncthreads();
        const int a = a0 + (t & 127);
        const int h0 = (t >> 7) * 512;
        float acc[8] = {};
#pragma unroll 4
        for (int h = 0; h < 512; ++h) {
            const float wv = wdec[(size_t)(h0 + h) * A_ + a];
#pragma unroll
            for (int j = 0; j < 8; ++j) acc[j] += hs[j][h0 + h] * wv;
        }
#pragma unroll
        for (int j = 0; j < 8; ++j) red[t][j] = acc[j];
        __syncthreads();
        if (t < 128) {
            const float bb = benc[a0 + t] + bdec[a0 + t];
#pragma unroll
            for (int j = 0; j < 8; ++j)
                att2p[(size_t)(b0 + j) * A_ + a0 + t] =
                    red[t][j] + red[t + 128][j] + bb;
        }
    } else if (bid < 256) {         // ---- wt: W_enc^T -> g_wt (bf16) ----
        __bf16* tile = (__bf16*)smem;           // [64][72]
        const int er = t >> 2, c0 = (t & 3) * 16;
        const int ar = t >> 2, es0 = (t & 3) * 16;
#pragma unroll 1
        for (int j = 0; j < 4; ++j) {
            const int job = (bid - 128) * 4 + j;        // 0..511
            const int a0 = (job & 15) * 64, e0 = (job >> 4) * 64;
            __syncthreads();        // tile reuse across jobs
#pragma unroll
            for (int jj = 0; jj < 4; ++jj) {
                const float4 v = *(const float4*)&w[(size_t)(e0 + er) * A_ +
                                                    a0 + c0 + jj * 4];
                tile[(c0 + jj * 4 + 0) * 72 + er] = (__bf16)v.x;
                tile[(c0 + jj * 4 + 1) * 72 + er] = (__bf16)v.y;
                tile[(c0 + jj * 4 + 2) * 72 + er] = (__bf16)v.z;
                tile[(c0 + jj * 4 + 3) * 72 + er] = (__bf16)v.w;
            }
            __syncthreads();
            *(bf16x8*)&g_wt[(size_t)(a0 + ar) * E_ + e0 + es0] =
                *(const bf16x8*)&tile[ar * 72 + es0];
            *(bf16x8*)&g_wt[(size_t)(a0 + ar) * E_ + e0 + es0 + 8] =
                *(const bf16x8*)&tile[ar * 72 + es0 + 8];
        }
    } else {                        // ---- cvt: enc -> g_enc (bf16) ----
        size_t i = ((size_t)(bid - 256) * 256 + t) * 8;
        const size_t stride = (size_t)1792 * 256 * 8;   // covers n in 14 steps
#pragma unroll
        for (int it = 0; it < 14; ++it, i += stride) {
            const float4 a = *(const float4*)(enc + i);
            const float4 b = *(const float4*)(enc + i + 4);
            *(bf16x8*)&g_enc[i] = cvt8r(a, b);
        }
    }
}

// ---------------------------------------------------------------------------
// K2: fused GEMM + bias + relu + W_full row-reduce -> atomicAdd scores[M].
// 8-phase schedule, 256x256 tile, BK=64, 8 waves (wm=w>>2, wn=w&3), each
// wave outputs 128x64 (8 m-frags x 4 n-frags of 16x16x32 bf16).
// LDS A: [slot2][half2][sg2][row64][128B]  (sg=wm; half mh = 64-row groups)
// LDS B: [slot2][half2][sg4][row32][128B]  (sg=wn; half nh = 32-col groups)
// Staged via global_load_lds, source pre-swizzled: LDS chunk c of row rr
// holds source chunk c ^ (rr&7); frag read XORs it back -> conflict-free.
// vmcnt(4) at phases 3/7 only (2 half-tiles in flight, never 0 in loop).
// XCD swizzle: nwg=392=8*49, L=(orig&7)*49+orig>>3, bn=L&3, bm=L>>2.
// (unchanged from round 12)
// ---------------------------------------------------------------------------
__global__ __launch_bounds__(512, 1) void k_gemm_scores(
    const float* __restrict__ att2p,    // [B_][A_] fp32
    const float* __restrict__ wfull,    // [A_] fp32
    float* __restrict__ scores) {       // [M_] fp32
    __shared__ __align__(16) __bf16 As[2][2][2][64][64];    // 64 KB
    __shared__ __align__(16) __bf16 Bs[2][2][4][32][64];    // 64 KB

    const int t = threadIdx.x;
    const int lane = t & 63, w = t >> 6;
    const int wm = w >> 2, wn = w & 3;
    const int q = lane >> 4, r = lane & 15;
    const int orig = blockIdx.x;                 // 0..391
    const int L = (orig & 7) * 49 + (orig >> 3); // bijective (392 = 8*49)
    const int bn = L & 3, bm = L >> 2;
    const int m0 = bm * 256, n0 = bn * 256;

    // staging source bases (row stride 4096 B in both g_enc and g_wt)
    const int swz = ((t & 7) ^ ((t >> 3) & 7)) * 16;
    const char* gA = (const char*)g_enc + (size_t)(m0 + (t >> 3)) * 4096 + swz;
    const char* gB = (const char*)g_wt +
        (size_t)(n0 + (t >> 8) * 64 + ((t >> 3) & 31)) * 4096 + swz;

    const int kx0 = (q * 16) ^ ((r & 7) << 4);
    const int kx1 = (64 + q * 16) ^ ((r & 7) << 4);

    bf16x8 af[4][2], bf0[2][2], bf1[2][2];
    f32x4 acc[8][4] = {};

// stage one half-tile (2 x gl16 per wave); kt = K-tile index
#define STG_A(slot, h, kt) do { \
    gl16(gA + ((size_t)(h) * 64) * 4096 + (size_t)(kt) * 128, \
         (char*)As + (slot) * 32768 + (h) * 16384 + w * 1024); \
    gl16(gA + ((size_t)(h) * 64 + 128) * 4096 + (size_t)(kt) * 128, \
         (char*)As + (slot) * 32768 + (h) * 16384 + 8192 + w * 1024); } while (0)
#define STG_B(slot, h, kt) do { \
    gl16(gB + ((size_t)(h) * 32) * 4096 + (size_t)(kt) * 128, \
         (char*)Bs + (slot) * 32768 + (h) * 16384 + w * 1024); \
    gl16(gB + ((size_t)(h) * 32 + 128) * 4096 + (size_t)(kt) * 128, \
         (char*)Bs + (slot) * 32768 + (h) * 16384 + 8192 + w * 1024); } while (0)

#define RD_A(slot, mh) do { \
    _Pragma("unroll") \
    for (int fl = 0; fl < 4; ++fl) { \
        const char* p_ = (const char*)As + (slot) * 32768 + (mh) * 16384 + \
                         wm * 8192 + (fl * 16 + r) * 128; \
        af[fl][0] = *(const bf16x8*)(p_ + kx0); \
        af[fl][1] = *(const bf16x8*)(p_ + kx1); } } while (0)
#define RD_B(slot, nh, B) do { \
    _Pragma("unroll") \
    for (int nl = 0; nl < 2; ++nl) { \
        const char* p_ = (const char*)Bs + (slot) * 32768 + (nh) * 16384 + \
                         wn * 4096 + (nl * 16 + r) * 128; \
        B[nl][0] = *(const bf16x8*)(p_ + kx0); \
        B[nl][1] = *(const bf16x8*)(p_ + kx1); } } while (0)
#define MM16(MH, NH, B) do { \
    _Pragma("unroll") \
    for (int fl = 0; fl < 4; ++fl) { \
        _Pragma("unroll") \
        for (int nl = 0; nl < 2; ++nl) { \
            acc[(MH)*4+fl][(NH)*2+nl] = __builtin_amdgcn_mfma_f32_16x16x32_bf16( \
                af[fl][0], B[nl][0], acc[(MH)*4+fl][(NH)*2+nl], 0, 0, 0); \
            acc[(MH)*4+fl][(NH)*2+nl] = __builtin_amdgcn_mfma_f32_16x16x32_bf16( \
                af[fl][1], B[nl][1], acc[(MH)*4+fl][(NH)*2+nl], 0, 0, 0); } } } while (0)
#define BAR() do { __builtin_amdgcn_sched_barrier(0); \
                   __builtin_amdgcn_s_barrier(); } while (0)
#define PRIO_MM(MH, NH, B) do { __builtin_amdgcn_s_setprio(1); \
    MM16(MH, NH, B); __builtin_amdgcn_s_setprio(0); } while (0)

    // ---- prologue: tile0 (all 4 halves) + tile1 (A0,B0); 12 gl16 ----
    STG_A(0, 0, 0); STG_B(0, 0, 0); STG_A(0, 1, 0); STG_B(0, 1, 0);
    STG_A(1, 0, 1); STG_B(1, 0, 1);
    asm volatile("s_waitcnt vmcnt(4)" ::: "memory");    // tile0 landed
    BAR();

    for (int i = 0; i < 15; ++i) {
        const int kb = 2 * i + 1, ka2 = 2 * i + 2, kb2 = 2 * i + 3;
        // p0: compute ka quad(0,0); stage A1(kb)
        RD_A(0, 0); RD_B(0, 0, bf0); STG_A(1, 1, kb); BAR();
        PRIO_MM(0, 0, bf0); BAR();
        // p1: quad(0,1); stage B1(kb)
        RD_B(0, 1, bf1); STG_B(1, 1, kb); BAR();
        PRIO_MM(0, 1, bf1); BAR();
        // p2: quad(1,0); stage A0(ka+2)
        RD_A(0, 1); STG_A(0, 0, ka2); BAR();
        PRIO_MM(1, 0, bf0); BAR();
        // p3: quad(1,1); stage B0(ka+2); WAIT -> kb fully landed
        STG_B(0, 0, ka2);
        asm volatile("s_waitcnt vmcnt(4)" ::: "memory");
        BAR();
        PRIO_MM(1, 1, bf1); BAR();
        // p4: compute kb quad(0,0); stage A1(ka+2)
        RD_A(1, 0); RD_B(1, 0, bf0); STG_A(0, 1, ka2); BAR();
        PRIO_MM(0, 0, bf0); BAR();
        // p5: quad(0,1); stage B1(ka+2)
        RD_B(1, 1, bf1); STG_B(0, 1, ka2); BAR();
        PRIO_MM(0, 1, bf1); BAR();
        // p6: quad(1,0); stage A0(kb+2)
        RD_A(1, 1); STG_A(1, 0, kb2); BAR();
        PRIO_MM(1, 0, bf0); BAR();
        // p7: quad(1,1); stage B0(kb+2); WAIT -> ka+2 fully landed
        STG_B(1, 0, kb2);
        asm volatile("s_waitcnt vmcnt(4)" ::: "memory");
        BAR();
        PRIO_MM(1, 1, bf1); BAR();
    }
    // ---- peeled tail: ka=30, kb=31; only A1/B1(31) still to stage ----
    RD_A(0, 0); RD_B(0, 0, bf0); STG_A(1, 1, 31); BAR();
    PRIO_MM(0, 0, bf0); BAR();
    RD_B(0, 1, bf1); STG_B(1, 1, 31); BAR();
    PRIO_MM(0, 1, bf1); BAR();
    RD_A(0, 1); BAR();
    PRIO_MM(1, 0, bf0); BAR();
    asm volatile("s_waitcnt vmcnt(0)" ::: "memory");    // tile31 landed
    BAR();
    PRIO_MM(1, 1, bf1); BAR();
    RD_A(1, 0); RD_B(1, 0, bf0); BAR();
    PRIO_MM(0, 0, bf0); BAR();
    RD_B(1, 1, bf1); BAR();
    PRIO_MM(0, 1, bf1); BAR();
    RD_A(1, 1); BAR();
    PRIO_MM(1, 0, bf0); BAR();
    BAR();
    PRIO_MM(1, 1, bf1); BAR();

    // ---- epilogue: bias+relu+wfull dot, reduce, atomicAdd ----
    // C/D: col(n) = r, row(m) = q*4+i. red overlays As (dead, 0 gl16 left).
    float* red = (float*)As;            // [256][4] floats
    const float* wfb = wfull + n0 + wn * 64;
#pragma unroll
    for (int f = 0; f < 8; ++f) {
#pragma unroll
        for (int i2 = 0; i2 < 4; ++i2) {
            const int row256 = wm * 128 + f * 16 + q * 4 + i2;
            const int row_g = m0 + row256;
            const unsigned bidx = (unsigned)row_g / 196u;
            const float* a2 = att2p + (size_t)bidx * A_ + n0 + wn * 64;
            float s = 0.f;
#pragma unroll
            for (int fn = 0; fn < 4; ++fn) {
                const int cl = fn * 16 + r;
                float v = acc[f][fn][i2] + a2[cl];
                v = fmaxf(v, 0.f);
                s += v * wfb[cl];
            }
            s += __shfl_xor(s, 1);
            s += __shfl_xor(s, 2);
            s += __shfl_xor(s, 4);
            s += __shfl_xor(s, 8);
            if (r == 0) red[row256 * 4 + wn] = s;
        }
    }
    __syncthreads();
    if (t < 256)
        atomicAdd(&scores[m0 + t],
                  red[t * 4] + red[t * 4 + 1] + red[t * 4 + 2] + red[t * 4 + 3]);
#undef STG_A
#undef STG_B
#undef RD_A
#undef RD_B
#undef MM16
#undef BAR
#undef PRIO_MM
}

// ---------------------------------------------------------------------------
// K3: softmax over P=196 per batch; alpha (fp32) -> d_out elems [262144,...).
// ---------------------------------------------------------------------------
__global__ __launch_bounds__(256) void k_softmax(
    const float* __restrict__ scores, float* __restrict__ out) {
    const int b = blockIdx.x;
    const int t = threadIdx.x;
    __shared__ float sm[256];
    const bool act = t < P_;
    const float val = act ? scores[b * P_ + t] : 0.f;
    sm[t] = act ? val : -1e30f;
    __syncthreads();
    for (int off = 128; off > 0; off >>= 1) {
        if (t < off) sm[t] = fmaxf(sm[t], sm[t + off]);
        __syncthreads();
    }
    const float mx = sm[0];
    __syncthreads();
    const float e = act ? __expf(val - mx) : 0.f;
    sm[t] = e;
    __syncthreads();
    for (int off = 128; off > 0; off >>= 1) {
        if (t < off) sm[t] = sm[t] + sm[t + off];
        __syncthreads();
    }
    const float inv = 1.0f / sm[0];
    if (act) out[(size_t)B_ * E_ + b * P_ + t] = e * inv;
}

// ---------------------------------------------------------------------------
// K4: context[b][e] = sum_p alpha[b][p] * g_enc[b][p][e]  (bf16 enc, fp32 acc)
// Grid (4 e-chunks of 512, 128 b) = 512 blocks (2/CU).
// ---------------------------------------------------------------------------
__global__ __launch_bounds__(256) void k_context(float* __restrict__ out) {
    const int b = blockIdx.y;
    const int e0 = blockIdx.x * 512 + threadIdx.x * 2;
    __shared__ float al[P_];
    if (threadIdx.x < P_)
        al[threadIdx.x] = out[(size_t)B_ * E_ + b * P_ + threadIdx.x];
    __syncthreads();
    float ax = 0.f, ay = 0.f;
    const char* base = (const char*)g_enc +
                       ((size_t)b * P_) * (E_ * 2) + (size_t)e0 * 2;
#pragma unroll 14
    for (int p = 0; p < P_; ++p) {
        const unsigned u = *(const unsigned*)(base + (size_t)p * (E_ * 2));
        const float ap = al[p];
        ax += ap * __uint_as_float(u << 16);
        ay += ap * __uint_as_float(u & 0xffff0000u);
    }
    float2 sv; sv.x = ax; sv.y = ay;
    *(float2*)(out + (size_t)b * E_ + e0) = sv;
}

// ---------------------------------------------------------------------------
extern "C" void kernel_launch(void* const* d_in, const int* in_sizes, int n_in,
                              void* d_out, int out_size, void* d_ws,
                              size_t ws_size, hipStream_t stream) {
    const float* enc   = (const float*)d_in[0];
    const float* dh    = (const float*)d_in[1];
    const float* wenc  = (const float*)d_in[2];
    const float* benc  = (const float*)d_in[3];
    const float* wdec  = (const float*)d_in[4];
    const float* bdec  = (const float*)d_in[5];
    const float* wfull = (const float*)d_in[6];
    // d_in[7] = b_full: softmax shift-invariant, unused
    float* out = (float*)d_out;

    float* att2p  = out;                              // bytes [0, 524288)
    float* scores = (float*)((char*)d_out + 524288);  // bytes [524288, 624640)

    k_pre<<<2048, 256, 0, stream>>>(enc, wenc, dh, wdec, benc, bdec, scores,
                                    att2p);
    k_gemm_scores<<<392, 512, 0, stream>>>(att2p, wfull, scores);
    k_softmax<<<B_, 256, 0, stream>>>(scores, out);
    k_context<<<dim3(4, B_), 256, 0, stream>>>(out);
}

// Round 7
// 511.610 us; speedup vs baseline: 1.1639x; 1.0017x over previous
//
#include <hip/hip_runtime.h>
#include <hip/hip_bf16.h>

// Show-Attend-Tell attention. B=128, P=196, E=2048, H=1024, A=1024.
// fp32 in / fp32 out (established round 6; passed absmax 1.95e-3).
// Round 14: k_pre LDS 40 KB -> 16 KB (occupancy 4 -> 8 blocks/CU).
//   Round-13 counters: k_pre 150 us @ 2.2 TB/s combined, VALU 4.7%, occ 27%
//   -> cvt branch capped at 16 waves/CU by the 40 KB smem of the att2
//   branch. att2 now uses 4 b-rows/block (hs[4][1024]=16 KB, red 4 KB
//   OVERLAYS hs after its last read), 256 blocks; cvt runs at 32 waves/CU.
// GEMM: 8-phase counted-vmcnt schedule (round 12; <=150 us, off top-5).
// Intermediates inside d_out (fp32, 287232 elems total):
//   bytes [0      : 524288)  att2' fp32 [B][A]   (dead after GEMM)
//   bytes [524288 : 624640)  scores fp32 [M]     (dead after softmax)
//   elems [262144 : 287232)  alpha fp32 (final)
//   elems [0      : 262144)  context fp32 (final, written LAST by k_context)

#define B_   128
#define P_   196
#define E_   2048
#define H_   1024
#define A_   1024
#define M_   (B_ * P_)      // 25088
#define NKSTEP (E_ / 64)    // 32

typedef __bf16 bf16x8 __attribute__((ext_vector_type(8)));
typedef float f32x4 __attribute__((ext_vector_type(4)));

// One-time converted operands (module globals):
__device__ __bf16 g_wt[(size_t)A_ * E_];    // 4 MB:  Wt[a][e] = bf16 W_enc[e][a]
__device__ __bf16 g_enc[(size_t)M_ * E_];   // 103 MB: bf16 enc[m][e]

__device__ __forceinline__ bf16x8 cvt8r(const float4 a, const float4 b) {
    bf16x8 r;
    r[0] = (__bf16)a.x; r[1] = (__bf16)a.y; r[2] = (__bf16)a.z; r[3] = (__bf16)a.w;
    r[4] = (__bf16)b.x; r[5] = (__bf16)b.y; r[6] = (__bf16)b.z; r[7] = (__bf16)b.w;
    return r;
}

// async 16B global->LDS (lds dest wave-uniform; HW adds lane*16)
__device__ __forceinline__ void gl16(const void* g, void* l) {
    __builtin_amdgcn_global_load_lds(
        (const __attribute__((address_space(1))) unsigned int*)g,
        (__attribute__((address_space(3))) unsigned int*)l, 16, 0, 0);
}

// ---------------------------------------------------------------------------
// K1: merged preprocessing. Grid 2176 x 256, 16 KB LDS (8 blocks/CU):
//   blocks [0,256):     zero scores; att2p[b][a] = benc+bdec+dh[b]@W_dec[:,a]
//                       (4 b-rows per block; red overlays hs)
//   blocks [256,384):   Wt[a][e] = bf16(W_enc[e][a]), 4 64x64 tiles each
//   blocks [384,2176):  g_enc = bf16(enc), grid-stride (exactly 14 sweeps)
// Latency-bound branches first; cvt at full 32 waves/CU occupancy.
// ---------------------------------------------------------------------------
__global__ __launch_bounds__(256) void k_pre(
    const float* __restrict__ enc, const float* __restrict__ w,
    const float* __restrict__ dh, const float* __restrict__ wdec,
    const float* __restrict__ benc, const float* __restrict__ bdec,
    float* __restrict__ scores, float* __restrict__ att2p) {
    __shared__ float smem[4096];    // 16 KB scratch, per-branch layout
    const int bid = blockIdx.x;
    const int t = threadIdx.x;

    if (bid < 256) {                // ---- att2 (+ zero scores) ----
        const int a0 = (bid & 7) * 128;
        const int b0 = (bid >> 3) * 4;          // 32 b-groups of 4
        // zero scores: 256 blocks x 128 = 32768 >= M_=25088 (use t<128 slot)
        const int gi = bid * 128 + t;
        if (t < 128 && gi + 0 < M_) {}          // (index math below)
        if (gi < M_) scores[gi] = 0.f;          // blocks 0..195 cover M_
        float (*hs)[H_] = (float (*)[H_])smem;  // [4][1024] 16 KB
        for (int i = t; i < 4 * H_; i += 256)
            hs[i >> 10][i & 1023] =
                dh[(size_t)(b0 + (i >> 10)) * H_ + (i & 1023)];
        __syncthreads();
        const int a = a0 + (t & 127);
        const int h0 = (t >> 7) * 512;
        float acc[4] = {};
#pragma unroll 4
        for (int h = 0; h < 512; ++h) {
            const float wv = wdec[(size_t)(h0 + h) * A_ + a];
#pragma unroll
            for (int j = 0; j < 4; ++j) acc[j] += hs[j][h0 + h] * wv;
        }
        __syncthreads();            // hs dead; red overlays smem
        float (*red)[4] = (float (*)[4])smem;   // [256][4] 4 KB
#pragma unroll
        for (int j = 0; j < 4; ++j) red[t][j] = acc[j];
        __syncthreads();
        if (t < 128) {
            const float bb = benc[a0 + t] + bdec[a0 + t];
#pragma unroll
            for (int j = 0; j < 4; ++j)
                att2p[(size_t)(b0 + j) * A_ + a0 + t] =
                    red[t][j] + red[t + 128][j] + bb;
        }
    } else if (bid < 384) {         // ---- wt: W_enc^T -> g_wt (bf16) ----
        __bf16* tile = (__bf16*)smem;           // [64][72] 9.2 KB
        const int er = t >> 2, c0 = (t & 3) * 16;
        const int ar = t >> 2, es0 = (t & 3) * 16;
#pragma unroll 1
        for (int j = 0; j < 4; ++j) {
            const int job = (bid - 256) * 4 + j;        // 0..511
            const int a0 = (job & 15) * 64, e0 = (job >> 4) * 64;
            __syncthreads();        // tile reuse across jobs
#pragma unroll
            for (int jj = 0; jj < 4; ++jj) {
                const float4 v = *(const float4*)&w[(size_t)(e0 + er) * A_ +
                                                    a0 + c0 + jj * 4];
                tile[(c0 + jj * 4 + 0) * 72 + er] = (__bf16)v.x;
                tile[(c0 + jj * 4 + 1) * 72 + er] = (__bf16)v.y;
                tile[(c0 + jj * 4 + 2) * 72 + er] = (__bf16)v.z;
                tile[(c0 + jj * 4 + 3) * 72 + er] = (__bf16)v.w;
            }
            __syncthreads();
            *(bf16x8*)&g_wt[(size_t)(a0 + ar) * E_ + e0 + es0] =
                *(const bf16x8*)&tile[ar * 72 + es0];
            *(bf16x8*)&g_wt[(size_t)(a0 + ar) * E_ + e0 + es0 + 8] =
                *(const bf16x8*)&tile[ar * 72 + es0 + 8];
        }
    } else {                        // ---- cvt: enc -> g_enc (bf16) ----
        size_t i = ((size_t)(bid - 384) * 256 + t) * 8;
        const size_t stride = (size_t)1792 * 256 * 8;   // covers n in 14 steps
#pragma unroll
        for (int it = 0; it < 14; ++it, i += stride) {
            const float4 a = *(const float4*)(enc + i);
            const float4 b = *(const float4*)(enc + i + 4);
            *(bf16x8*)&g_enc[i] = cvt8r(a, b);
        }
    }
}

// ---------------------------------------------------------------------------
// K2: fused GEMM + bias + relu + W_full row-reduce -> atomicAdd scores[M].
// 8-phase schedule, 256x256 tile, BK=64, 8 waves (wm=w>>2, wn=w&3), each
// wave outputs 128x64 (8 m-frags x 4 n-frags of 16x16x32 bf16).
// LDS A: [slot2][half2][sg2][row64][128B]  (sg=wm; half mh = 64-row groups)
// LDS B: [slot2][half2][sg4][row32][128B]  (sg=wn; half nh = 32-col groups)
// Staged via global_load_lds, source pre-swizzled: LDS chunk c of row rr
// holds source chunk c ^ (rr&7); frag read XORs it back -> conflict-free.
// vmcnt(4) at phases 3/7 only (2 half-tiles in flight, never 0 in loop).
// XCD swizzle: nwg=392=8*49, L=(orig&7)*49+orig>>3, bn=L&3, bm=L>>2.
// (unchanged from round 12)
// ---------------------------------------------------------------------------
__global__ __launch_bounds__(512, 1) void k_gemm_scores(
    const float* __restrict__ att2p,    // [B_][A_] fp32
    const float* __restrict__ wfull,    // [A_] fp32
    float* __restrict__ scores) {       // [M_] fp32
    __shared__ __align__(16) __bf16 As[2][2][2][64][64];    // 64 KB
    __shared__ __align__(16) __bf16 Bs[2][2][4][32][64];    // 64 KB

    const int t = threadIdx.x;
    const int lane = t & 63, w = t >> 6;
    const int wm = w >> 2, wn = w & 3;
    const int q = lane >> 4, r = lane & 15;
    const int orig = blockIdx.x;                 // 0..391
    const int L = (orig & 7) * 49 + (orig >> 3); // bijective (392 = 8*49)
    const int bn = L & 3, bm = L >> 2;
    const int m0 = bm * 256, n0 = bn * 256;

    // staging source bases (row stride 4096 B in both g_enc and g_wt)
    const int swz = ((t & 7) ^ ((t >> 3) & 7)) * 16;
    const char* gA = (const char*)g_enc + (size_t)(m0 + (t >> 3)) * 4096 + swz;
    const char* gB = (const char*)g_wt +
        (size_t)(n0 + (t >> 8) * 64 + ((t >> 3) & 31)) * 4096 + swz;

    const int kx0 = (q * 16) ^ ((r & 7) << 4);
    const int kx1 = (64 + q * 16) ^ ((r & 7) << 4);

    bf16x8 af[4][2], bf0[2][2], bf1[2][2];
    f32x4 acc[8][4] = {};

// stage one half-tile (2 x gl16 per wave); kt = K-tile index
#define STG_A(slot, h, kt) do { \
    gl16(gA + ((size_t)(h) * 64) * 4096 + (size_t)(kt) * 128, \
         (char*)As + (slot) * 32768 + (h) * 16384 + w * 1024); \
    gl16(gA + ((size_t)(h) * 64 + 128) * 4096 + (size_t)(kt) * 128, \
         (char*)As + (slot) * 32768 + (h) * 16384 + 8192 + w * 1024); } while (0)
#define STG_B(slot, h, kt) do { \
    gl16(gB + ((size_t)(h) * 32) * 4096 + (size_t)(kt) * 128, \
         (char*)Bs + (slot) * 32768 + (h) * 16384 + w * 1024); \
    gl16(gB + ((size_t)(h) * 32 + 128) * 4096 + (size_t)(kt) * 128, \
         (char*)Bs + (slot) * 32768 + (h) * 16384 + 8192 + w * 1024); } while (0)

#define RD_A(slot, mh) do { \
    _Pragma("unroll") \
    for (int fl = 0; fl < 4; ++fl) { \
        const char* p_ = (const char*)As + (slot) * 32768 + (mh) * 16384 + \
                         wm * 8192 + (fl * 16 + r) * 128; \
        af[fl][0] = *(const bf16x8*)(p_ + kx0); \
        af[fl][1] = *(const bf16x8*)(p_ + kx1); } } while (0)
#define RD_B(slot, nh, B) do { \
    _Pragma("unroll") \
    for (int nl = 0; nl < 2; ++nl) { \
        const char* p_ = (const char*)Bs + (slot) * 32768 + (nh) * 16384 + \
                         wn * 4096 + (nl * 16 + r) * 128; \
        B[nl][0] = *(const bf16x8*)(p_ + kx0); \
        B[nl][1] = *(const bf16x8*)(p_ + kx1); } } while (0)
#define MM16(MH, NH, B) do { \
    _Pragma("unroll") \
    for (int fl = 0; fl < 4; ++fl) { \
        _Pragma("unroll") \
        for (int nl = 0; nl < 2; ++nl) { \
            acc[(MH)*4+fl][(NH)*2+nl] = __builtin_amdgcn_mfma_f32_16x16x32_bf16( \
                af[fl][0], B[nl][0], acc[(MH)*4+fl][(NH)*2+nl], 0, 0, 0); \
            acc[(MH)*4+fl][(NH)*2+nl] = __builtin_amdgcn_mfma_f32_16x16x32_bf16( \
                af[fl][1], B[nl][1], acc[(MH)*4+fl][(NH)*2+nl], 0, 0, 0); } } } while (0)
#define BAR() do { __builtin_amdgcn_sched_barrier(0); \
                   __builtin_amdgcn_s_barrier(); } while (0)
#define PRIO_MM(MH, NH, B) do { __builtin_amdgcn_s_setprio(1); \
    MM16(MH, NH, B); __builtin_amdgcn_s_setprio(0); } while (0)

    // ---- prologue: tile0 (all 4 halves) + tile1 (A0,B0); 12 gl16 ----
    STG_A(0, 0, 0); STG_B(0, 0, 0); STG_A(0, 1, 0); STG_B(0, 1, 0);
    STG_A(1, 0, 1); STG_B(1, 0, 1);
    asm volatile("s_waitcnt vmcnt(4)" ::: "memory");    // tile0 landed
    BAR();

    for (int i = 0; i < 15; ++i) {
        const int kb = 2 * i + 1, ka2 = 2 * i + 2, kb2 = 2 * i + 3;
        // p0: compute ka quad(0,0); stage A1(kb)
        RD_A(0, 0); RD_B(0, 0, bf0); STG_A(1, 1, kb); BAR();
        PRIO_MM(0, 0, bf0); BAR();
        // p1: quad(0,1); stage B1(kb)
        RD_B(0, 1, bf1); STG_B(1, 1, kb); BAR();
        PRIO_MM(0, 1, bf1); BAR();
        // p2: quad(1,0); stage A0(ka+2)
        RD_A(0, 1); STG_A(0, 0, ka2); BAR();
        PRIO_MM(1, 0, bf0); BAR();
        // p3: quad(1,1); stage B0(ka+2); WAIT -> kb fully landed
        STG_B(0, 0, ka2);
        asm volatile("s_waitcnt vmcnt(4)" ::: "memory");
        BAR();
        PRIO_MM(1, 1, bf1); BAR();
        // p4: compute kb quad(0,0); stage A1(ka+2)
        RD_A(1, 0); RD_B(1, 0, bf0); STG_A(0, 1, ka2); BAR();
        PRIO_MM(0, 0, bf0); BAR();
        // p5: quad(0,1); stage B1(ka+2)
        RD_B(1, 1, bf1); STG_B(0, 1, ka2); BAR();
        PRIO_MM(0, 1, bf1); BAR();
        // p6: quad(1,0); stage A0(kb+2)
        RD_A(1, 1); STG_A(1, 0, kb2); BAR();
        PRIO_MM(1, 0, bf0); BAR();
        // p7: quad(1,1); stage B0(kb+2); WAIT -> ka+2 fully landed
        STG_B(1, 0, kb2);
        asm volatile("s_waitcnt vmcnt(4)" ::: "memory");
        BAR();
        PRIO_MM(1, 1, bf1); BAR();
    }
    // ---- peeled tail: ka=30, kb=31; only A1/B1(31) still to stage ----
    RD_A(0, 0); RD_B(0, 0, bf0); STG_A(1, 1, 31); BAR();
    PRIO_MM(0, 0, bf0); BAR();
    RD_B(0, 1, bf1); STG_B(1, 1, 31); BAR();
    PRIO_MM(0, 1, bf1); BAR();
    RD_A(0, 1); BAR();
    PRIO_MM(1, 0, bf0); BAR();
    asm volatile("s_waitcnt vmcnt(0)" ::: "memory");    // tile31 landed
    BAR();
    PRIO_MM(1, 1, bf1); BAR();
    RD_A(1, 0); RD_B(1, 0, bf0); BAR();
    PRIO_MM(0, 0, bf0); BAR();
    RD_B(1, 1, bf1); BAR();
    PRIO_MM(0, 1, bf1); BAR();
    RD_A(1, 1); BAR();
    PRIO_MM(1, 0, bf0); BAR();
    BAR();
    PRIO_MM(1, 1, bf1); BAR();

    // ---- epilogue: bias+relu+wfull dot, reduce, atomicAdd ----
    // C/D: col(n) = r, row(m) = q*4+i. red overlays As (dead, 0 gl16 left).
    float* red = (float*)As;            // [256][4] floats
    const float* wfb = wfull + n0 + wn * 64;
#pragma unroll
    for (int f = 0; f < 8; ++f) {
#pragma unroll
        for (int i2 = 0; i2 < 4; ++i2) {
            const int row256 = wm * 128 + f * 16 + q * 4 + i2;
            const int row_g = m0 + row256;
            const unsigned bidx = (unsigned)row_g / 196u;
            const float* a2 = att2p + (size_t)bidx * A_ + n0 + wn * 64;
            float s = 0.f;
#pragma unroll
            for (int fn = 0; fn < 4; ++fn) {
                const int cl = fn * 16 + r;
                float v = acc[f][fn][i2] + a2[cl];
                v = fmaxf(v, 0.f);
                s += v * wfb[cl];
            }
            s += __shfl_xor(s, 1);
            s += __shfl_xor(s, 2);
            s += __shfl_xor(s, 4);
            s += __shfl_xor(s, 8);
            if (r == 0) red[row256 * 4 + wn] = s;
        }
    }
    __syncthreads();
    if (t < 256)
        atomicAdd(&scores[m0 + t],
                  red[t * 4] + red[t * 4 + 1] + red[t * 4 + 2] + red[t * 4 + 3]);
#undef STG_A
#undef STG_B
#undef RD_A
#undef RD_B
#undef MM16
#undef BAR
#undef PRIO_MM
}

// ---------------------------------------------------------------------------
// K3: softmax over P=196 per batch; alpha (fp32) -> d_out elems [262144,...).
// ---------------------------------------------------------------------------
__global__ __launch_bounds__(256) void k_softmax(
    const float* __restrict__ scores, float* __restrict__ out) {
    const int b = blockIdx.x;
    const int t = threadIdx.x;
    __shared__ float sm[256];
    const bool act = t < P_;
    const float val = act ? scores[b * P_ + t] : 0.f;
    sm[t] = act ? val : -1e30f;
    __syncthreads();
    for (int off = 128; off > 0; off >>= 1) {
        if (t < off) sm[t] = fmaxf(sm[t], sm[t + off]);
        __syncthreads();
    }
    const float mx = sm[0];
    __syncthreads();
    const float e = act ? __expf(val - mx) : 0.f;
    sm[t] = e;
    __syncthreads();
    for (int off = 128; off > 0; off >>= 1) {
        if (t < off) sm[t] = sm[t] + sm[t + off];
        __syncthreads();
    }
    const float inv = 1.0f / sm[0];
    if (act) out[(size_t)B_ * E_ + b * P_ + t] = e * inv;
}

// ---------------------------------------------------------------------------
// K4: context[b][e] = sum_p alpha[b][p] * g_enc[b][p][e]  (bf16 enc, fp32 acc)
// Grid (4 e-chunks of 512, 128 b) = 512 blocks (2/CU).
// ---------------------------------------------------------------------------
__global__ __launch_bounds__(256) void k_context(float* __restrict__ out) {
    const int b = blockIdx.y;
    const int e0 = blockIdx.x * 512 + threadIdx.x * 2;
    __shared__ float al[P_];
    if (threadIdx.x < P_)
        al[threadIdx.x] = out[(size_t)B_ * E_ + b * P_ + threadIdx.x];
    __syncthreads();
    float ax = 0.f, ay = 0.f;
    const char* base = (const char*)g_enc +
                       ((size_t)b * P_) * (E_ * 2) + (size_t)e0 * 2;
#pragma unroll 14
    for (int p = 0; p < P_; ++p) {
        const unsigned u = *(const unsigned*)(base + (size_t)p * (E_ * 2));
        const float ap = al[p];
        ax += ap * __uint_as_float(u << 16);
        ay += ap * __uint_as_float(u & 0xffff0000u);
    }
    float2 sv; sv.x = ax; sv.y = ay;
    *(float2*)(out + (size_t)b * E_ + e0) = sv;
}

// ---------------------------------------------------------------------------
extern "C" void kernel_launch(void* const* d_in, const int* in_sizes, int n_in,
                              void* d_out, int out_size, void* d_ws,
                              size_t ws_size, hipStream_t stream) {
    const float* enc   = (const float*)d_in[0];
    const float* dh    = (const float*)d_in[1];
    const float* wenc  = (const float*)d_in[2];
    const float* benc  = (const float*)d_in[3];
    const float* wdec  = (const float*)d_in[4];
    const float* bdec  = (const float*)d_in[5];
    const float* wfull = (const float*)d_in[6];
    // d_in[7] = b_full: softmax shift-invariant, unused
    float* out = (float*)d_out;

    float* att2p  = out;                              // bytes [0, 524288)
    float* scores = (float*)((char*)d_out + 524288);  // bytes [524288, 624640)

    k_pre<<<2176, 256, 0, stream>>>(enc, wenc, dh, wdec, benc, bdec, scores,
                                    att2p);
    k_gemm_scores<<<392, 512, 0, stream>>>(att2p, wfull, scores);
    k_softmax<<<B_, 256, 0, stream>>>(scores, out);
    k_context<<<dim3(4, B_), 256, 0, stream>>>(out);
}

// Round 8
// 490.481 us; speedup vs baseline: 1.2140x; 1.0431x over previous
//
#include <hip/hip_runtime.h>
#include <hip/hip_bf16.h>

// Show-Attend-Tell attention. B=128, P=196, E=2048, H=1024, A=1024.
// fp32 in / fp32 out (established round 6; passed absmax 1.95e-3).
// Round 15: k_pre att2 de-serialization.
//   r13/r14 invariance (150 us regardless of occupancy) isolated the cost:
//   att2's 4x ds_read_b32 per h (8192 LDS instrs/block) x 8 blocks packed
//   per CU = 380k cy = 158 us on the att2 CUs. Two fixes:
//   (1) hs layout [1024][4]: ONE broadcast ds_read_b128 per h (reads / 4);
//   (2) branch spread by bid%17 (coprime to 8-XCD round-robin): att2/wt
//       land ~1-2 per CU instead of 8; cvt rank via mod-17 arithmetic.
//   cvt (~56 us, BW-bound) becomes the k_pre pole; att2 hides under it.
// GEMM: 8-phase counted-vmcnt schedule (round 12; ~151 us, top-1 now).
// Intermediates inside d_out (fp32, 287232 elems total):
//   bytes [0      : 524288)  att2' fp32 [B][A]   (dead after GEMM)
//   bytes [524288 : 624640)  scores fp32 [M]     (dead after softmax)
//   elems [262144 : 287232)  alpha fp32 (final)
//   elems [0      : 262144)  context fp32 (final, written LAST by k_context)

#define B_   128
#define P_   196
#define E_   2048
#define H_   1024
#define A_   1024
#define M_   (B_ * P_)      // 25088
#define NKSTEP (E_ / 64)    // 32

typedef __bf16 bf16x8 __attribute__((ext_vector_type(8)));
typedef float f32x4 __attribute__((ext_vector_type(4)));

// One-time converted operands (module globals):
__device__ __bf16 g_wt[(size_t)A_ * E_];    // 4 MB:  Wt[a][e] = bf16 W_enc[e][a]
__device__ __bf16 g_enc[(size_t)M_ * E_];   // 103 MB: bf16 enc[m][e]

__device__ __forceinline__ bf16x8 cvt8r(const float4 a, const float4 b) {
    bf16x8 r;
    r[0] = (__bf16)a.x; r[1] = (__bf16)a.y; r[2] = (__bf16)a.z; r[3] = (__bf16)a.w;
    r[4] = (__bf16)b.x; r[5] = (__bf16)b.y; r[6] = (__bf16)b.z; r[7] = (__bf16)b.w;
    return r;
}

// async 16B global->LDS (lds dest wave-uniform; HW adds lane*16)
__device__ __forceinline__ void gl16(const void* g, void* l) {
    __builtin_amdgcn_global_load_lds(
        (const __attribute__((address_space(1))) unsigned int*)g,
        (__attribute__((address_space(3))) unsigned int*)l, 16, 0, 0);
}

// ---------------------------------------------------------------------------
// K1: merged preprocessing. Grid 2176 = 128 groups of 17; within each group:
//   off==0 or 8:  att2 (256 blocks total, SPREAD across CUs/XCDs)
//   off==4:       wt   (128 blocks total)
//   else (14/17): cvt  (1792 blocks, dense rank = grp*14 + g(off))
// 16 KB LDS everywhere (8 blocks/CU). 17 is coprime to the XCD round-robin,
// so special blocks never pile onto one XCD/CU.
// ---------------------------------------------------------------------------
__global__ __launch_bounds__(256) void k_pre(
    const float* __restrict__ enc, const float* __restrict__ w,
    const float* __restrict__ dh, const float* __restrict__ wdec,
    const float* __restrict__ benc, const float* __restrict__ bdec,
    float* __restrict__ scores, float* __restrict__ att2p) {
    __shared__ float smem[4096];    // 16 KB scratch, per-branch layout
    const int bid = blockIdx.x;
    const int t = threadIdx.x;
    const int grp = bid / 17;       // 0..127
    const int off = bid % 17;

    if (off == 0 || off == 8) {     // ---- att2 (+ zero scores) ----
        const int vbid = grp * 2 + (off >> 3);  // 0..255
        const int a0 = (vbid & 7) * 128;
        const int b0 = (vbid >> 3) * 4;         // 32 b-groups of 4
        const int gi = vbid * 128 + t;
        if (gi < M_) scores[gi] = 0.f;          // zero before GEMM atomicAdd
        float (*hs4)[4] = (float (*)[4])smem;   // [1024][4] h-major, 16 KB
        for (int i = t; i < 4 * H_; i += 256) {
            const int j = i >> 10, h = i & 1023;
            hs4[h][j] = dh[(size_t)(b0 + j) * H_ + h];
        }
        __syncthreads();
        const int a = a0 + (t & 127);
        const int h0 = (t >> 7) * 512;
        float ac0 = 0.f, ac1 = 0.f, ac2 = 0.f, ac3 = 0.f;
#pragma unroll 8
        for (int h = 0; h < 512; ++h) {
            const float wv = wdec[(size_t)(h0 + h) * A_ + a];
            const float4 hv = *(const float4*)&hs4[h0 + h][0];  // b128 bcast
            ac0 += hv.x * wv; ac1 += hv.y * wv;
            ac2 += hv.z * wv; ac3 += hv.w * wv;
        }
        __syncthreads();            // hs4 dead; red overlays smem
        float (*red)[4] = (float (*)[4])smem;   // [256][4] 4 KB
        red[t][0] = ac0; red[t][1] = ac1; red[t][2] = ac2; red[t][3] = ac3;
        __syncthreads();
        if (t < 128) {
            const float bb = benc[a0 + t] + bdec[a0 + t];
#pragma unroll
            for (int j = 0; j < 4; ++j)
                att2p[(size_t)(b0 + j) * A_ + a0 + t] =
                    red[t][j] + red[t + 128][j] + bb;
        }
    } else if (off == 4) {          // ---- wt: W_enc^T -> g_wt (bf16) ----
        __bf16* tile = (__bf16*)smem;           // [64][72] 9.2 KB
        const int er = t >> 2, c0 = (t & 3) * 16;
        const int ar = t >> 2, es0 = (t & 3) * 16;
#pragma unroll 1
        for (int j = 0; j < 4; ++j) {
            const int job = grp * 4 + j;                // 0..511
            const int a0 = (job & 15) * 64, e0 = (job >> 4) * 64;
            __syncthreads();        // tile reuse across jobs
#pragma unroll
            for (int jj = 0; jj < 4; ++jj) {
                const float4 v = *(const float4*)&w[(size_t)(e0 + er) * A_ +
                                                    a0 + c0 + jj * 4];
                tile[(c0 + jj * 4 + 0) * 72 + er] = (__bf16)v.x;
                tile[(c0 + jj * 4 + 1) * 72 + er] = (__bf16)v.y;
                tile[(c0 + jj * 4 + 2) * 72 + er] = (__bf16)v.z;
                tile[(c0 + jj * 4 + 3) * 72 + er] = (__bf16)v.w;
            }
            __syncthreads();
            *(bf16x8*)&g_wt[(size_t)(a0 + ar) * E_ + e0 + es0] =
                *(const bf16x8*)&tile[ar * 72 + es0];
            *(bf16x8*)&g_wt[(size_t)(a0 + ar) * E_ + e0 + es0 + 8] =
                *(const bf16x8*)&tile[ar * 72 + es0 + 8];
        }
    } else {                        // ---- cvt: enc -> g_enc (bf16) ----
        // dense rank over the 14 non-special offsets of each 17-group
        const int g = off - 1 - (off > 4) - (off > 8);  // 0..13
        const int rank = grp * 14 + g;                  // 0..1791
        size_t i = ((size_t)rank * 256 + t) * 8;
        const size_t stride = (size_t)1792 * 256 * 8;   // covers n in 14 steps
#pragma unroll
        for (int it = 0; it < 14; ++it, i += stride) {
            const float4 a = *(const float4*)(enc + i);
            const float4 b = *(const float4*)(enc + i + 4);
            *(bf16x8*)&g_enc[i] = cvt8r(a, b);
        }
    }
}

// ---------------------------------------------------------------------------
// K2: fused GEMM + bias + relu + W_full row-reduce -> atomicAdd scores[M].
// 8-phase schedule, 256x256 tile, BK=64, 8 waves (wm=w>>2, wn=w&3), each
// wave outputs 128x64 (8 m-frags x 4 n-frags of 16x16x32 bf16).
// LDS A: [slot2][half2][sg2][row64][128B]  (sg=wm; half mh = 64-row groups)
// LDS B: [slot2][half2][sg4][row32][128B]  (sg=wn; half nh = 32-col groups)
// Staged via global_load_lds, source pre-swizzled: LDS chunk c of row rr
// holds source chunk c ^ (rr&7); frag read XORs it back -> conflict-free.
// vmcnt(4) at phases 3/7 only (2 half-tiles in flight, never 0 in loop).
// XCD swizzle: nwg=392=8*49, L=(orig&7)*49+orig>>3, bn=L&3, bm=L>>2.
// (unchanged from round 12)
// ---------------------------------------------------------------------------
__global__ __launch_bounds__(512, 1) void k_gemm_scores(
    const float* __restrict__ att2p,    // [B_][A_] fp32
    const float* __restrict__ wfull,    // [A_] fp32
    float* __restrict__ scores) {       // [M_] fp32
    __shared__ __align__(16) __bf16 As[2][2][2][64][64];    // 64 KB
    __shared__ __align__(16) __bf16 Bs[2][2][4][32][64];    // 64 KB

    const int t = threadIdx.x;
    const int lane = t & 63, w = t >> 6;
    const int wm = w >> 2, wn = w & 3;
    const int q = lane >> 4, r = lane & 15;
    const int orig = blockIdx.x;                 // 0..391
    const int L = (orig & 7) * 49 + (orig >> 3); // bijective (392 = 8*49)
    const int bn = L & 3, bm = L >> 2;
    const int m0 = bm * 256, n0 = bn * 256;

    // staging source bases (row stride 4096 B in both g_enc and g_wt)
    const int swz = ((t & 7) ^ ((t >> 3) & 7)) * 16;
    const char* gA = (const char*)g_enc + (size_t)(m0 + (t >> 3)) * 4096 + swz;
    const char* gB = (const char*)g_wt +
        (size_t)(n0 + (t >> 8) * 64 + ((t >> 3) & 31)) * 4096 + swz;

    const int kx0 = (q * 16) ^ ((r & 7) << 4);
    const int kx1 = (64 + q * 16) ^ ((r & 7) << 4);

    bf16x8 af[4][2], bf0[2][2], bf1[2][2];
    f32x4 acc[8][4] = {};

// stage one half-tile (2 x gl16 per wave); kt = K-tile index
#define STG_A(slot, h, kt) do { \
    gl16(gA + ((size_t)(h) * 64) * 4096 + (size_t)(kt) * 128, \
         (char*)As + (slot) * 32768 + (h) * 16384 + w * 1024); \
    gl16(gA + ((size_t)(h) * 64 + 128) * 4096 + (size_t)(kt) * 128, \
         (char*)As + (slot) * 32768 + (h) * 16384 + 8192 + w * 1024); } while (0)
#define STG_B(slot, h, kt) do { \
    gl16(gB + ((size_t)(h) * 32) * 4096 + (size_t)(kt) * 128, \
         (char*)Bs + (slot) * 32768 + (h) * 16384 + w * 1024); \
    gl16(gB + ((size_t)(h) * 32 + 128) * 4096 + (size_t)(kt) * 128, \
         (char*)Bs + (slot) * 32768 + (h) * 16384 + 8192 + w * 1024); } while (0)

#define RD_A(slot, mh) do { \
    _Pragma("unroll") \
    for (int fl = 0; fl < 4; ++fl) { \
        const char* p_ = (const char*)As + (slot) * 32768 + (mh) * 16384 + \
                         wm * 8192 + (fl * 16 + r) * 128; \
        af[fl][0] = *(const bf16x8*)(p_ + kx0); \
        af[fl][1] = *(const bf16x8*)(p_ + kx1); } } while (0)
#define RD_B(slot, nh, B) do { \
    _Pragma("unroll") \
    for (int nl = 0; nl < 2; ++nl) { \
        const char* p_ = (const char*)Bs + (slot) * 32768 + (nh) * 16384 + \
                         wn * 4096 + (nl * 16 + r) * 128; \
        B[nl][0] = *(const bf16x8*)(p_ + kx0); \
        B[nl][1] = *(const bf16x8*)(p_ + kx1); } } while (0)
#define MM16(MH, NH, B) do { \
    _Pragma("unroll") \
    for (int fl = 0; fl < 4; ++fl) { \
        _Pragma("unroll") \
        for (int nl = 0; nl < 2; ++nl) { \
            acc[(MH)*4+fl][(NH)*2+nl] = __builtin_amdgcn_mfma_f32_16x16x32_bf16( \
                af[fl][0], B[nl][0], acc[(MH)*4+fl][(NH)*2+nl], 0, 0, 0); \
            acc[(MH)*4+fl][(NH)*2+nl] = __builtin_amdgcn_mfma_f32_16x16x32_bf16( \
                af[fl][1], B[nl][1], acc[(MH)*4+fl][(NH)*2+nl], 0, 0, 0); } } } while (0)
#define BAR() do { __builtin_amdgcn_sched_barrier(0); \
                   __builtin_amdgcn_s_barrier(); } while (0)
#define PRIO_MM(MH, NH, B) do { __builtin_amdgcn_s_setprio(1); \
    MM16(MH, NH, B); __builtin_amdgcn_s_setprio(0); } while (0)

    // ---- prologue: tile0 (all 4 halves) + tile1 (A0,B0); 12 gl16 ----
    STG_A(0, 0, 0); STG_B(0, 0, 0); STG_A(0, 1, 0); STG_B(0, 1, 0);
    STG_A(1, 0, 1); STG_B(1, 0, 1);
    asm volatile("s_waitcnt vmcnt(4)" ::: "memory");    // tile0 landed
    BAR();

    for (int i = 0; i < 15; ++i) {
        const int kb = 2 * i + 1, ka2 = 2 * i + 2, kb2 = 2 * i + 3;
        // p0: compute ka quad(0,0); stage A1(kb)
        RD_A(0, 0); RD_B(0, 0, bf0); STG_A(1, 1, kb); BAR();
        PRIO_MM(0, 0, bf0); BAR();
        // p1: quad(0,1); stage B1(kb)
        RD_B(0, 1, bf1); STG_B(1, 1, kb); BAR();
        PRIO_MM(0, 1, bf1); BAR();
        // p2: quad(1,0); stage A0(ka+2)
        RD_A(0, 1); STG_A(0, 0, ka2); BAR();
        PRIO_MM(1, 0, bf0); BAR();
        // p3: quad(1,1); stage B0(ka+2); WAIT -> kb fully landed
        STG_B(0, 0, ka2);
        asm volatile("s_waitcnt vmcnt(4)" ::: "memory");
        BAR();
        PRIO_MM(1, 1, bf1); BAR();
        // p4: compute kb quad(0,0); stage A1(ka+2)
        RD_A(1, 0); RD_B(1, 0, bf0); STG_A(0, 1, ka2); BAR();
        PRIO_MM(0, 0, bf0); BAR();
        // p5: quad(0,1); stage B1(ka+2)
        RD_B(1, 1, bf1); STG_B(0, 1, ka2); BAR();
        PRIO_MM(0, 1, bf1); BAR();
        // p6: quad(1,0); stage A0(kb+2)
        RD_A(1, 1); STG_A(1, 0, kb2); BAR();
        PRIO_MM(1, 0, bf0); BAR();
        // p7: quad(1,1); stage B0(kb+2); WAIT -> ka+2 fully landed
        STG_B(1, 0, kb2);
        asm volatile("s_waitcnt vmcnt(4)" ::: "memory");
        BAR();
        PRIO_MM(1, 1, bf1); BAR();
    }
    // ---- peeled tail: ka=30, kb=31; only A1/B1(31) still to stage ----
    RD_A(0, 0); RD_B(0, 0, bf0); STG_A(1, 1, 31); BAR();
    PRIO_MM(0, 0, bf0); BAR();
    RD_B(0, 1, bf1); STG_B(1, 1, 31); BAR();
    PRIO_MM(0, 1, bf1); BAR();
    RD_A(0, 1); BAR();
    PRIO_MM(1, 0, bf0); BAR();
    asm volatile("s_waitcnt vmcnt(0)" ::: "memory");    // tile31 landed
    BAR();
    PRIO_MM(1, 1, bf1); BAR();
    RD_A(1, 0); RD_B(1, 0, bf0); BAR();
    PRIO_MM(0, 0, bf0); BAR();
    RD_B(1, 1, bf1); BAR();
    PRIO_MM(0, 1, bf1); BAR();
    RD_A(1, 1); BAR();
    PRIO_MM(1, 0, bf0); BAR();
    BAR();
    PRIO_MM(1, 1, bf1); BAR();

    // ---- epilogue: bias+relu+wfull dot, reduce, atomicAdd ----
    // C/D: col(n) = r, row(m) = q*4+i. red overlays As (dead, 0 gl16 left).
    float* red = (float*)As;            // [256][4] floats
    const float* wfb = wfull + n0 + wn * 64;
#pragma unroll
    for (int f = 0; f < 8; ++f) {
#pragma unroll
        for (int i2 = 0; i2 < 4; ++i2) {
            const int row256 = wm * 128 + f * 16 + q * 4 + i2;
            const int row_g = m0 + row256;
            const unsigned bidx = (unsigned)row_g / 196u;
            const float* a2 = att2p + (size_t)bidx * A_ + n0 + wn * 64;
            float s = 0.f;
#pragma unroll
            for (int fn = 0; fn < 4; ++fn) {
                const int cl = fn * 16 + r;
                float v = acc[f][fn][i2] + a2[cl];
                v = fmaxf(v, 0.f);
                s += v * wfb[cl];
            }
            s += __shfl_xor(s, 1);
            s += __shfl_xor(s, 2);
            s += __shfl_xor(s, 4);
            s += __shfl_xor(s, 8);
            if (r == 0) red[row256 * 4 + wn] = s;
        }
    }
    __syncthreads();
    if (t < 256)
        atomicAdd(&scores[m0 + t],
                  red[t * 4] + red[t * 4 + 1] + red[t * 4 + 2] + red[t * 4 + 3]);
#undef STG_A
#undef STG_B
#undef RD_A
#undef RD_B
#undef MM16
#undef BAR
#undef PRIO_MM
}

// ---------------------------------------------------------------------------
// K3: softmax over P=196 per batch; alpha (fp32) -> d_out elems [262144,...).
// ---------------------------------------------------------------------------
__global__ __launch_bounds__(256) void k_softmax(
    const float* __restrict__ scores, float* __restrict__ out) {
    const int b = blockIdx.x;
    const int t = threadIdx.x;
    __shared__ float sm[256];
    const bool act = t < P_;
    const float val = act ? scores[b * P_ + t] : 0.f;
    sm[t] = act ? val : -1e30f;
    __syncthreads();
    for (int off = 128; off > 0; off >>= 1) {
        if (t < off) sm[t] = fmaxf(sm[t], sm[t + off]);
        __syncthreads();
    }
    const float mx = sm[0];
    __syncthreads();
    const float e = act ? __expf(val - mx) : 0.f;
    sm[t] = e;
    __syncthreads();
    for (int off = 128; off > 0; off >>= 1) {
        if (t < off) sm[t] = sm[t] + sm[t + off];
        __syncthreads();
    }
    const float inv = 1.0f / sm[0];
    if (act) out[(size_t)B_ * E_ + b * P_ + t] = e * inv;
}

// ---------------------------------------------------------------------------
// K4: context[b][e] = sum_p alpha[b][p] * g_enc[b][p][e]  (bf16 enc, fp32 acc)
// Grid (4 e-chunks of 512, 128 b) = 512 blocks (2/CU).
// ---------------------------------------------------------------------------
__global__ __launch_bounds__(256) void k_context(float* __restrict__ out) {
    const int b = blockIdx.y;
    const int e0 = blockIdx.x * 512 + threadIdx.x * 2;
    __shared__ float al[P_];
    if (threadIdx.x < P_)
        al[threadIdx.x] = out[(size_t)B_ * E_ + b * P_ + threadIdx.x];
    __syncthreads();
    float ax = 0.f, ay = 0.f;
    const char* base = (const char*)g_enc +
                       ((size_t)b * P_) * (E_ * 2) + (size_t)e0 * 2;
#pragma unroll 14
    for (int p = 0; p < P_; ++p) {
        const unsigned u = *(const unsigned*)(base + (size_t)p * (E_ * 2));
        const float ap = al[p];
        ax += ap * __uint_as_float(u << 16);
        ay += ap * __uint_as_float(u & 0xffff0000u);
    }
    float2 sv; sv.x = ax; sv.y = ay;
    *(float2*)(out + (size_t)b * E_ + e0) = sv;
}

// ---------------------------------------------------------------------------
extern "C" void kernel_launch(void* const* d_in, const int* in_sizes, int n_in,
                              void* d_out, int out_size, void* d_ws,
                              size_t ws_size, hipStream_t stream) {
    const float* enc   = (const float*)d_in[0];
    const float* dh    = (const float*)d_in[1];
    const float* wenc  = (const float*)d_in[2];
    const float* benc  = (const float*)d_in[3];
    const float* wdec  = (const float*)d_in[4];
    const float* bdec  = (const float*)d_in[5];
    const float* wfull = (const float*)d_in[6];
    // d_in[7] = b_full: softmax shift-invariant, unused
    float* out = (float*)d_out;

    float* att2p  = out;                              // bytes [0, 524288)
    float* scores = (float*)((char*)d_out + 524288);  // bytes [524288, 624640)

    k_pre<<<2176, 256, 0, stream>>>(enc, wenc, dh, wdec, benc, bdec, scores,
                                    att2p);
    k_gemm_scores<<<392, 512, 0, stream>>>(att2p, wfull, scores);
    k_softmax<<<B_, 256, 0, stream>>>(scores, out);
    k_context<<<dim3(4, B_), 256, 0, stream>>>(out);
}